// Round 8
// baseline (1250.416 us; speedup 1.0000x reference)
//
#include <hip/hip_runtime.h>
#include <hip/hip_bf16.h>

// ============================================================================
// HWNet-SPP forward, MFMA bf16 implicit-GEMM with selective hi/lo precision.
// GEMM is barrier-free: A/B fragments load DIRECTLY from global to VGPRs
// (no LDS staging; LDS only holds the fused-BN reduction buffer).
// Pass config per layer (error budget vs absmax threshold 0.098):
//   conv2: Ah*Bh                (1-pass)   conv3: Ah*Bh + Al*Bh  (2-pass)
//   conv4: Ah*Bh                (1-pass)   conv5: full 3-pass hi/lo
//   FC1/FC2: Ah*Bh + Al*Bh      (2-pass)
// BN column stats fused into GEMM epilogue (SPLIT==1) or split-K reducer.
// Conv/FC biases skipped (BN mean-subtraction cancels them exactly).
// ============================================================================

typedef __bf16 bf16;
using bf16x4 = __attribute__((ext_vector_type(4))) __bf16;
using bf16x8 = __attribute__((ext_vector_type(8))) __bf16;
using f32x4  = __attribute__((ext_vector_type(4))) float;

__device__ __forceinline__ void split2(float v, bf16& h, bf16& l) {
  bf16 hb = (bf16)v;
  h = hb;
  l = (bf16)(v - (float)hb);
}

// ---------------- pad (edge mode, +2 each side of 48x128) ----------------
__global__ __launch_bounds__(256) void pad_edge_k(const float* __restrict__ x,
                                                  float* __restrict__ p) {
  int i = blockIdx.x * 256 + threadIdx.x;
  const int TOT = 64 * 52 * 132;
  if (i >= TOT) return;
  int w = i % 132; int t = i / 132; int h = t % 52; int n = t / 52;
  int sh = h - 2; sh = sh < 0 ? 0 : (sh > 47 ? 47 : sh);
  int sw = w - 2; sw = sw < 0 ? 0 : (sw > 127 ? 127 : sw);
  p[i] = x[(n * 48 + sh) * 128 + sw];
}

// ---------------- conv1 pass 1: BN stats only (fp32, recompute style) ------
__global__ __launch_bounds__(256) void conv1_stats_k(const float* __restrict__ P,
                                                     const float* __restrict__ wt,
                                                     float* __restrict__ part) {
  int co0 = blockIdx.y * 8;
  float sums[8] = {0.f}, sqs[8] = {0.f};
  for (int r = 0; r < 16; r++) {
    int pix = blockIdx.x * 4096 + r * 256 + threadIdx.x;  // 0..393215
    int w = pix & 127; int t = pix >> 7; int h = t % 48; int n = t / 48;
    const float* ip = P + ((size_t)n * 52 + h) * 132 + w;
    float win[25];
#pragma unroll
    for (int kh = 0; kh < 5; kh++)
#pragma unroll
      for (int kw = 0; kw < 5; kw++) win[kh * 5 + kw] = ip[kh * 132 + kw];
#pragma unroll
    for (int j = 0; j < 8; j++) {
      const float* wp = wt + (size_t)(co0 + j) * 25;
      float acc = 0.f;
#pragma unroll
      for (int k = 0; k < 25; k++) acc += win[k] * wp[k];
      sums[j] += acc; sqs[j] += acc * acc;
    }
  }
  __shared__ float ls[256], lq[256];
  for (int j = 0; j < 8; j++) {
    ls[threadIdx.x] = sums[j]; lq[threadIdx.x] = sqs[j];
    __syncthreads();
    for (int o = 128; o > 0; o >>= 1) {
      if (threadIdx.x < o) { ls[threadIdx.x] += ls[threadIdx.x + o]; lq[threadIdx.x] += lq[threadIdx.x + o]; }
      __syncthreads();
    }
    if (threadIdx.x == 0) {
      int c = co0 + j;
      part[((size_t)c * 96 + blockIdx.x) * 2 + 0] = ls[0];
      part[((size_t)c * 96 + blockIdx.x) * 2 + 1] = lq[0];
    }
    __syncthreads();
  }
}

// ---------------- conv1 pass 2: conv+BN+ReLU+pool+pad -> hi/lo -------------
__global__ __launch_bounds__(256) void conv1_apply_k(const float* __restrict__ P,
                                                     const float* __restrict__ wt,
                                                     const float* __restrict__ scale,
                                                     const float* __restrict__ shift,
                                                     bf16* __restrict__ yh,
                                                     bf16* __restrict__ yl) {
  int pix = blockIdx.x * 256 + threadIdx.x;  // 0..98303
  int ow = pix & 63; int t = pix >> 6; int oh = t % 24; int n = t / 24;
  int co0 = blockIdx.y * 8;
  const float* ip = P + ((size_t)n * 52 + 2 * oh) * 132 + 2 * ow;
  float win[36];
#pragma unroll
  for (int r = 0; r < 6; r++)
#pragma unroll
    for (int c = 0; c < 6; c++) win[r * 6 + c] = ip[r * 132 + c];
  bf16x8 hv, lv;
#pragma unroll
  for (int j = 0; j < 8; j++) {
    const float* wp = wt + (size_t)(co0 + j) * 25;
    float sc = scale[co0 + j], sh = shift[co0 + j];
    float m = -1e30f;
#pragma unroll
    for (int dy = 0; dy < 2; dy++)
#pragma unroll
      for (int dx = 0; dx < 2; dx++) {
        float acc = 0.f;
#pragma unroll
        for (int kh = 0; kh < 5; kh++)
#pragma unroll
          for (int kw = 0; kw < 5; kw++)
            acc += win[(kh + dy) * 6 + kw + dx] * wp[kh * 5 + kw];
        m = fmaxf(m, acc * sc + sh);
      }
    float v = fmaxf(m, 0.f);
    bf16 h, l; split2(v, h, l);
    hv[j] = h; lv[j] = l;
  }
  size_t o = (((size_t)n * 28 + oh + 2) * 68 + ow + 2) * 64 + co0;
  *(bf16x8*)(yh + o) = hv;
  *(bf16x8*)(yl + o) = lv;
}

// ---------------- MFMA implicit-GEMM, direct-register, selective hi/lo -----
// C[m,co] = Ah.Bh (+ Al.Bh if ALO) (+ Ah.Bl if BLO)
// A from padded NHWC bf16 [64][OH+KS-1][OW+KS-1][CI]; FC: KS=1,OH=OW=2.
// Tile 128x128, BK=64, 4 waves (2x2). No LDS staging, no K-loop barriers:
// each lane loads its MFMA fragments (16B) straight from global memory.
template<int CI, int KS, int OH, int OW, int CO, bool ALO, bool BLO, int SPLIT>
__global__ __launch_bounds__(256) void conv_gemm_k(const bf16* __restrict__ Ahi,
                                                   const bf16* __restrict__ Alo,
                                                   const bf16* __restrict__ Bhi,
                                                   const bf16* __restrict__ Blo,
                                                   float* __restrict__ Cout,
                                                   float* __restrict__ part) {
  static_assert(CI % 64 == 0, "chunk must not straddle ci segments");
  constexpr int K = KS * KS * CI;
  constexpr int IWP = OW + KS - 1;
  constexpr int NCH = K / 64;
  static_assert(NCH % SPLIT == 0, "split must divide chunk count");
  constexpr int NCHS = NCH / SPLIT;
  constexpr int M = 64 * OH * OW;
  __shared__ float red[2][128][8];
  const int t = threadIdx.x;
  const int lane = t & 63, w = t >> 6;
  const int m0 = blockIdx.x * 128, n0 = blockIdx.y * 128;
  const int z = (SPLIT > 1) ? blockIdx.z : 0;
  const int wrow = w >> 1, wcol = w & 1;
  const int kg = lane >> 4, l15 = lane & 15;

  // per-lane fragment base offsets (element units, kg*8 folded in)
  int abase[4], bbase[4];
#pragma unroll
  for (int q = 0; q < 4; q++) {
    int m = m0 + wrow * 64 + q * 16 + l15;
    int n = m / (OH * OW); int rem = m % (OH * OW);
    int oh = rem / OW, ow_ = rem % OW;
    abase[q] = ((n * (OH + KS - 1) + oh) * IWP + ow_) * CI + kg * 8;
    bbase[q] = (n0 + wcol * 64 + q * 16 + l15) * K + kg * 8;
  }

  f32x4 acc[4][4] = {};
  for (int kc = z * NCHS; kc < (z + 1) * NCHS; ++kc) {
    const int k0 = kc * 64;
    const int seg = k0 / CI;
    const int ci0 = k0 % CI;
    const int kh = seg / KS, kw = seg % KS;
    const int aoff = (kh * IWP + kw) * CI + ci0;   // wave-uniform
#pragma unroll
    for (int ks = 0; ks < 2; ks++) {
      const int off = ks * 32;  // (ks*4 slots) * 8 elems
      bf16x8 ah[4], bh[4];
#pragma unroll
      for (int q = 0; q < 4; q++) {
        ah[q] = *(const bf16x8*)(Ahi + (size_t)(abase[q] + aoff + off));
        bh[q] = *(const bf16x8*)(Bhi + (size_t)(bbase[q] + k0 + off));
      }
#pragma unroll
      for (int mi = 0; mi < 4; mi++)
#pragma unroll
        for (int ni = 0; ni < 4; ni++)
          acc[mi][ni] = __builtin_amdgcn_mfma_f32_16x16x32_bf16(ah[mi], bh[ni], acc[mi][ni], 0, 0, 0);
      if (ALO) {
        bf16x8 al[4];
#pragma unroll
        for (int q = 0; q < 4; q++)
          al[q] = *(const bf16x8*)(Alo + (size_t)(abase[q] + aoff + off));
#pragma unroll
        for (int mi = 0; mi < 4; mi++)
#pragma unroll
          for (int ni = 0; ni < 4; ni++)
            acc[mi][ni] = __builtin_amdgcn_mfma_f32_16x16x32_bf16(al[mi], bh[ni], acc[mi][ni], 0, 0, 0);
      }
      if (BLO) {
        bf16x8 bl[4];
#pragma unroll
        for (int q = 0; q < 4; q++)
          bl[q] = *(const bf16x8*)(Blo + (size_t)(bbase[q] + k0 + off));
#pragma unroll
        for (int mi = 0; mi < 4; mi++)
#pragma unroll
          for (int ni = 0; ni < 4; ni++)
            acc[mi][ni] = __builtin_amdgcn_mfma_f32_16x16x32_bf16(ah[mi], bl[ni], acc[mi][ni], 0, 0, 0);
      }
    }
  }

  // epilogue: D row = (lane>>4)*4 + jj, col = lane&15
  const int crow0 = kg * 4, ccol = l15;
  float* Cz = Cout + (size_t)z * M * CO;
#pragma unroll
  for (int mi = 0; mi < 4; mi++) {
    int m = m0 + wrow * 64 + mi * 16 + crow0;
#pragma unroll
    for (int ni = 0; ni < 4; ni++) {
      int nn = n0 + wcol * 64 + ni * 16 + ccol;
      float* cp = Cz + (size_t)m * CO + nn;
#pragma unroll
      for (int jj = 0; jj < 4; jj++) cp[(size_t)jj * CO] = acc[mi][ni][jj];
    }
  }
  if constexpr (SPLIT == 1) {
    // fused BN partials: per-thread 16-row sums per owned column
    const int contrib = kg * 2 + wrow;  // 8 contributors per column
#pragma unroll
    for (int ni = 0; ni < 4; ni++) {
      float s = 0.f, q = 0.f;
#pragma unroll
      for (int mi = 0; mi < 4; mi++)
#pragma unroll
        for (int jj = 0; jj < 4; jj++) {
          float v = acc[mi][ni][jj];
          s += v; q += v * v;
        }
      int coll = wcol * 64 + ni * 16 + ccol;
      red[0][coll][contrib] = s;
      red[1][coll][contrib] = q;
    }
    __syncthreads();
    if (t < 128) {
      float s = 0.f, q = 0.f;
#pragma unroll
      for (int j = 0; j < 8; j++) { s += red[0][t][j]; q += red[1][t][j]; }
      size_t c = n0 + t;
      part[(c * gridDim.x + blockIdx.x) * 2 + 0] = s;
      part[(c * gridDim.x + blockIdx.x) * 2 + 1] = q;
    }
  }
}

// ---------------- split-K reduction + BN partials ----------------
template<int M, int CO, int SPLIT, int NS>
__global__ __launch_bounds__(256) void reduce_bn_k(const float* __restrict__ Cp,
                                                   float* __restrict__ Cf,
                                                   float* __restrict__ part) {
  int c = blockIdx.x * 64 + (threadIdx.x & 63);
  int rl = threadIdx.x >> 6;
  constexpr int ROWS = M / NS;
  int r0 = blockIdx.y * ROWS;
  float sum = 0.f, sq = 0.f;
  for (int r = r0 + rl; r < r0 + ROWS; r += 4) {
    float v = 0.f;
#pragma unroll
    for (int s = 0; s < SPLIT; s++) v += Cp[(size_t)s * M * CO + (size_t)r * CO + c];
    Cf[(size_t)r * CO + c] = v;
    sum += v; sq += v * v;
  }
  __shared__ float ls[256], lq[256];
  ls[threadIdx.x] = sum; lq[threadIdx.x] = sq;
  __syncthreads();
  if (threadIdx.x < 64) {
    sum = ls[threadIdx.x] + ls[threadIdx.x + 64] + ls[threadIdx.x + 128] + ls[threadIdx.x + 192];
    sq  = lq[threadIdx.x] + lq[threadIdx.x + 64] + lq[threadIdx.x + 128] + lq[threadIdx.x + 192];
    part[((size_t)c * NS + blockIdx.y) * 2 + 0] = sum;
    part[((size_t)c * NS + blockIdx.y) * 2 + 1] = sq;
  }
}

__global__ void bn_finalize(const float* __restrict__ part,
                            const float* __restrict__ g, const float* __restrict__ b,
                            float* __restrict__ scale, float* __restrict__ shift,
                            int C, int S, float invCount) {
  int c = blockIdx.x * blockDim.x + threadIdx.x;
  if (c >= C) return;
  float sum = 0.f, sq = 0.f;
  for (int s = 0; s < S; s++) { sum += part[((size_t)c * S + s) * 2]; sq += part[((size_t)c * S + s) * 2 + 1]; }
  float m = sum * invCount;
  float var = sq * invCount - m * m;
  float sc = g[c] * rsqrtf(var + 1e-5f);
  scale[c] = sc;
  shift[c] = b[c] - m * sc;
}

// ---------------- fused BN + ReLU (+2x2 pool) + pad, fp32 -> hi/lo ---------
// Index space covers the PADDED output; halo lanes write zeros (no memset).
template<int CO, int IH, int IW, bool POOL, int PADO>
__global__ __launch_bounds__(256) void bn_act_pad_k(const float* __restrict__ x,
                                                    const float* __restrict__ scale,
                                                    const float* __restrict__ shift,
                                                    bf16* __restrict__ yh,
                                                    bf16* __restrict__ yl) {
  constexpr int OH2 = POOL ? IH / 2 : IH, OW2 = POOL ? IW / 2 : IW;
  constexpr int OHP = OH2 + 2 * PADO, OWP = OW2 + 2 * PADO;
  int i = blockIdx.x * 256 + threadIdx.x;
  if (i >= 64 * OHP * OWP * CO) return;
  int c = i % CO; int t = i / CO; int owp = t % OWP; t /= OWP; int ohp = t % OHP; int n = t / OHP;
  int oh = ohp - PADO, ow = owp - PADO;
  float v = 0.f;
  if (oh >= 0 && oh < OH2 && ow >= 0 && ow < OW2) {
    float sc = scale[c], sh = shift[c];
    if (POOL) {
      const float* p = x + (((size_t)(n * IH) + oh * 2) * IW + ow * 2) * CO + c;
      float a = p[0] * sc + sh;
      float b2 = p[CO] * sc + sh;
      float d = p[(size_t)IW * CO] * sc + sh;
      float e = p[(size_t)(IW + 1) * CO] * sc + sh;
      v = fmaxf(fmaxf(a, b2), fmaxf(d, e));
    } else {
      v = x[(((size_t)(n * OH2) + oh) * OW2 + ow) * CO + c] * sc + sh;
    }
    v = fmaxf(v, 0.f);
  }
  bf16 h, l; split2(v, h, l);
  yh[i] = h; yl[i] = l;
}

// ---------------- ROI SPP: feat hi/lo [64][6][16][512] -> S hi/lo ----------
__global__ __launch_bounds__(256) void spp_k(const bf16* __restrict__ fh,
                                             const bf16* __restrict__ fl,
                                             const int* __restrict__ roi,
                                             bf16* __restrict__ oh_,
                                             bf16* __restrict__ ol_) {
  int c = blockIdx.x * 256 + threadIdx.x;  // 0..511
  int r = blockIdx.y;                      // 0..255
  const int* rp = roi + r * 5;
  int im = rp[0];
  int c1 = rp[1] >> 3, r1 = rp[2] >> 3, c2 = rp[3] >> 3, r2 = rp[4] >> 3;
  int w = c2 - c1 + 1;
  int lo[6], hi[6];
  int bi = 0;
#pragma unroll
  for (int l = 1; l <= 3; l++)
    for (int k = 0; k < l; k++) {
      lo[bi] = c1 + (k * w) / l;
      hi[bi] = c1 + ((k + 1) * w + l - 1) / l - 1;
      bi++;
    }
  float mx[6];
#pragma unroll
  for (int b = 0; b < 6; b++) mx[b] = -1e30f;
  const bf16* ph = fh + (size_t)im * 96 * 512 + c;
  const bf16* pl = fl + (size_t)im * 96 * 512 + c;
  for (int row = r1; row <= r2; row++)
    for (int col = c1; col <= c2; col++) {
      size_t off = (size_t)(row * 16 + col) * 512;
      float v = (float)ph[off] + (float)pl[off];
#pragma unroll
      for (int b = 0; b < 6; b++)
        if (col >= lo[b] && col <= hi[b]) mx[b] = fmaxf(mx[b], v);
    }
  int idx[6] = {c, 512 + c * 2, 512 + c * 2 + 1, 1536 + c * 3, 1536 + c * 3 + 1, 1536 + c * 3 + 2};
#pragma unroll
  for (int b = 0; b < 6; b++) {
    bf16 h, l; split2(mx[b], h, l);
    oh_[(size_t)r * 3072 + idx[b]] = h;
    ol_[(size_t)r * 3072 + idx[b]] = l;
  }
}

// FC1: BN+ReLU, write hi/lo into CC[:, 0:2048] (ld 8192)
__global__ __launch_bounds__(256) void bn1d_apply_cc_k(const float* __restrict__ x,
                                                       const float* __restrict__ scale,
                                                       const float* __restrict__ shift,
                                                       bf16* __restrict__ ch,
                                                       bf16* __restrict__ cl) {
  int i = blockIdx.x * 256 + threadIdx.x;
  if (i >= 256 * 2048) return;
  int f = i & 2047, r = i >> 11;
  float v = fmaxf(x[i] * scale[f] + shift[f], 0.f);
  bf16 h, l; split2(v, h, l);
  ch[(size_t)r * 8192 + f] = h;
  cl[(size_t)r * 8192 + f] = l;
}

// FC2: BN+ReLU, fp32 out
__global__ __launch_bounds__(256) void bn1d_apply_f32_k(const float* __restrict__ x,
                                                        const float* __restrict__ scale,
                                                        const float* __restrict__ shift,
                                                        float* __restrict__ y) {
  int i = blockIdx.x * 256 + threadIdx.x;
  if (i >= 256 * 2048) return;
  int f = i & 2047;
  y[i] = fmaxf(x[i] * scale[f] + shift[f], 0.f);
}

// ---------------- weight transforms ----------------
template<int CI, int CO, int KS>
__global__ __launch_bounds__(256) void wconv_k(const float* __restrict__ w,
                                               bf16* __restrict__ oh_,
                                               bf16* __restrict__ ol_) {
  int i = blockIdx.x * 256 + threadIdx.x;
  if (i >= CO * KS * KS * CI) return;
  int ci = i % CI; int t = i / CI; int kw = t % KS; t /= KS; int kh = t % KS; int co = t / KS;
  float v = w[(((size_t)co * CI + ci) * KS + kh) * KS + kw];
  bf16 h, l; split2(v, h, l);
  oh_[i] = h;
  if (ol_) ol_[i] = l;
}

// fp32 -> bf16 cast, 4 elems/thread (n multiple of 4)
__global__ __launch_bounds__(256) void cast_k(const float* __restrict__ x,
                                              bf16* __restrict__ y, int n4) {
  int i = blockIdx.x * 256 + threadIdx.x;
  if (i >= n4) return;
  const float4 v = *(const float4*)(x + (size_t)i * 4);
  bf16x4 o = { (bf16)v.x, (bf16)v.y, (bf16)v.z, (bf16)v.w };
  *(bf16x4*)(y + (size_t)i * 4) = o;
}

// f2w [2048][7901] fp32 -> [2048][8192] bf16 hi (zero tail), 4 elems/thread
__global__ __launch_bounds__(256) void wfc2_k(const float* __restrict__ x,
                                              bf16* __restrict__ y) {
  int i = blockIdx.x * 256 + threadIdx.x;
  if (i >= 2048 * 2048) return;
  int k = (i & 2047) * 4, n = i >> 11;
  const float* xp = x + (size_t)n * 7901 + k;
  bf16x4 o;
#pragma unroll
  for (int j = 0; j < 4; j++) o[j] = (bf16)((k + j < 7901) ? xp[j] : 0.f);
  *(bf16x4*)(y + (size_t)n * 8192 + k) = o;
}

// phoc [256][5853] fp32 -> CC[:, 2048:8192] hi/lo (zero tail cols)
__global__ __launch_bounds__(256) void phoc_cc_k(const float* __restrict__ phoc,
                                                 bf16* __restrict__ ch,
                                                 bf16* __restrict__ cl) {
  int i = blockIdx.x * 256 + threadIdx.x;
  if (i >= 256 * 6144) return;
  int k = i % 6144, r = i / 6144;
  int col = 2048 + k;
  float v = (col < 7901) ? phoc[(size_t)r * 5853 + (col - 2048)] : 0.f;
  bf16 h, l; split2(v, h, l);
  ch[(size_t)r * 8192 + col] = h;
  cl[(size_t)r * 8192 + col] = l;
}

// ============================================================================
extern "C" void kernel_launch(void* const* d_in, const int* in_sizes, int n_in,
                              void* d_out, int out_size, void* d_ws, size_t ws_size,
                              hipStream_t stream) {
  (void)in_sizes; (void)n_in; (void)out_size; (void)ws_size;

  const float* x    = (const float*)d_in[0];
  const int*   roi  = (const int*)  d_in[1];
  const float* phoc = (const float*)d_in[2];
  const float* c1w  = (const float*)d_in[3];
  const float* g1   = (const float*)d_in[5];
  const float* b1   = (const float*)d_in[6];
  const float* c2w  = (const float*)d_in[7];
  const float* g2   = (const float*)d_in[9];
  const float* b2   = (const float*)d_in[10];
  const float* c3w  = (const float*)d_in[11];
  const float* g3   = (const float*)d_in[13];
  const float* b3   = (const float*)d_in[14];
  const float* c4w  = (const float*)d_in[15];
  const float* g4   = (const float*)d_in[17];
  const float* b4   = (const float*)d_in[18];
  const float* c5w  = (const float*)d_in[19];
  const float* g5   = (const float*)d_in[21];
  const float* b5   = (const float*)d_in[22];
  const float* f1w  = (const float*)d_in[23];
  const float* g6   = (const float*)d_in[25];
  const float* b6   = (const float*)d_in[26];
  const float* f2w  = (const float*)d_in[27];
  const float* g7   = (const float*)d_in[29];
  const float* b7   = (const float*)d_in[30];
  float* out = (float*)d_out;

  // ---- workspace layout (total ~168.4 MB) ----
  char* ws = (char*)d_ws;
  float* P    = (float*)(ws + 0x0000000);   // 1.76 MB
  bf16*  Ahi  = (bf16*) (ws + 0x0200000);   // 16 MB
  bf16*  Alo  = (bf16*) (ws + 0x1200000);   // 16 MB
  float* C    = (float*)(ws + 0x2200000);   // 51 MB region (GEMM out / split slabs)
  float* C5F  = (float*)(ws + 0x4200000);   // conv5 final (32MB into C region)
  bf16*  Wc2h = (bf16*) (ws + 0x5500000);
  bf16*  Wc3h = (bf16*) (ws + 0x5570000);
  bf16*  Wc4h = (bf16*) (ws + 0x5600000);
  bf16*  Wc5h = (bf16*) (ws + 0x5840000);
  bf16*  Wf1  = (bf16*) (ws + 0x5CC0000);
  bf16*  Wf2  = (bf16*) (ws + 0x68C0000);   // [2048][8192] = 32 MB
  bf16*  Wc5l = (bf16*) (ws + 0x8C00000);
  bf16*  Shi  = (bf16*) (ws + 0x9080000);   // spp out hi [256][3072]
  bf16*  Slo  = (bf16*) (ws + 0x9200000);
  float* G6   = (float*)(ws + 0x9380000);   // fc1 out fp32 [256][2048]
  bf16*  CChi = (bf16*) (ws + 0x9580000);   // concat hi [256][8192] = 4 MB
  bf16*  CClo = (bf16*) (ws + 0x9980000);
  float* G7   = (float*)(ws + 0x9D80000);   // fc2 out fp32 [256][2048]
  float* PART = (float*)(ws + 0x9F80000);   // 768 KB
  float* SC   = (float*)(ws + 0xA040000);
  float* SH   = (float*)(ws + 0xA050000);

  // ---- weight transforms ----
  wconv_k<64, 128, 5><<<800, 256, 0, stream>>>(c2w, Wc2h, nullptr);
  wconv_k<128, 256, 3><<<1152, 256, 0, stream>>>(c3w, Wc3h, nullptr);
  wconv_k<256, 512, 3><<<4608, 256, 0, stream>>>(c4w, Wc4h, nullptr);
  wconv_k<512, 512, 3><<<9216, 256, 0, stream>>>(c5w, Wc5h, Wc5l);
  cast_k<<<6144, 256, 0, stream>>>(f1w, Wf1, 2048 * 3072 / 4);
  wfc2_k<<<16384, 256, 0, stream>>>(f2w, Wf2);
  phoc_cc_k<<<6144, 256, 0, stream>>>(phoc, CChi, CClo);

  // ---- conv1 (two-pass, no big fp32 buffer) ----
  pad_edge_k<<<1716, 256, 0, stream>>>(x, P);
  conv1_stats_k<<<dim3(96, 8), 256, 0, stream>>>(P, c1w, PART);
  bn_finalize<<<1, 64, 0, stream>>>(PART, g1, b1, SC, SH, 64, 96, 1.f / 393216.f);
  hipMemsetAsync(Ahi, 0, (size_t)64 * 28 * 68 * 64 * 2, stream);
  hipMemsetAsync(Alo, 0, (size_t)64 * 28 * 68 * 64 * 2, stream);
  conv1_apply_k<<<dim3(384, 8), 256, 0, stream>>>(P, c1w, SC, SH, Ahi, Alo);

  // ---- conv2 (1-pass): A[98304][1600] -> C[98304][128] ----
  conv_gemm_k<64, 5, 24, 64, 128, false, false, 1><<<dim3(768, 1), 256, 0, stream>>>(Ahi, Alo, Wc2h, nullptr, C, PART);
  bn_finalize<<<1, 128, 0, stream>>>(PART, g2, b2, SC, SH, 128, 768, 1.f / 98304.f);
  bn_act_pad_k<128, 24, 64, true, 1><<<15232, 256, 0, stream>>>(C, SC, SH, Ahi, Alo);

  // ---- conv3 (2-pass: Ah.Bh + Al.Bh) ----
  conv_gemm_k<128, 3, 12, 32, 256, true, false, 1><<<dim3(192, 2), 256, 0, stream>>>(Ahi, Alo, Wc3h, nullptr, C, PART);
  bn_finalize<<<1, 256, 0, stream>>>(PART, g3, b3, SC, SH, 256, 192, 1.f / 24576.f);
  bn_act_pad_k<256, 12, 32, false, 1><<<30464, 256, 0, stream>>>(C, SC, SH, Ahi, Alo);

  // ---- conv4 (1-pass) ----
  conv_gemm_k<256, 3, 12, 32, 512, false, false, 1><<<dim3(192, 4), 256, 0, stream>>>(Ahi, Alo, Wc4h, nullptr, C, PART);
  bn_finalize<<<2, 256, 0, stream>>>(PART, g4, b4, SC, SH, 512, 192, 1.f / 24576.f);
  bn_act_pad_k<512, 12, 32, true, 1><<<18432, 256, 0, stream>>>(C, SC, SH, Ahi, Alo);

  // ---- conv5 (3-pass, split-K=2): partial slabs in C, final in C5F ----
  conv_gemm_k<512, 3, 6, 16, 512, true, true, 2><<<dim3(48, 4, 2), 256, 0, stream>>>(Ahi, Alo, Wc5h, Wc5l, C, nullptr);
  reduce_bn_k<6144, 512, 2, 16><<<dim3(8, 16), 256, 0, stream>>>(C, C5F, PART);
  bn_finalize<<<2, 256, 0, stream>>>(PART, g5, b5, SC, SH, 512, 16, 1.f / 6144.f);
  bn_act_pad_k<512, 6, 16, false, 0><<<12288, 256, 0, stream>>>(C5F, SC, SH, Ahi, Alo);  // feat

  // ---- SPP ----
  spp_k<<<dim3(2, 256), 256, 0, stream>>>(Ahi, Alo, roi, Shi, Slo);

  // ---- FC1 (2-pass, split-K=8): [256][3072] x [2048][3072] ----
  conv_gemm_k<3072, 1, 2, 2, 2048, true, false, 8><<<dim3(2, 16, 8), 256, 0, stream>>>(Shi, Slo, Wf1, nullptr, C, nullptr);
  reduce_bn_k<256, 2048, 8, 4><<<dim3(32, 4), 256, 0, stream>>>(C, G6, PART);
  bn_finalize<<<8, 256, 0, stream>>>(PART, g6, b6, SC, SH, 2048, 4, 1.f / 256.f);
  bn1d_apply_cc_k<<<2048, 256, 0, stream>>>(G6, SC, SH, CChi, CClo);

  // ---- FC2 (2-pass, split-K=8): [256][8192] x [2048][8192] ----
  conv_gemm_k<8192, 1, 2, 2, 2048, true, false, 8><<<dim3(2, 16, 8), 256, 0, stream>>>(CChi, CClo, Wf2, nullptr, C, nullptr);
  reduce_bn_k<256, 2048, 8, 4><<<dim3(32, 4), 256, 0, stream>>>(C, G7, PART);
  bn_finalize<<<8, 256, 0, stream>>>(PART, g7, b7, SC, SH, 2048, 4, 1.f / 256.f);
  bn1d_apply_f32_k<<<2048, 256, 0, stream>>>(G7, SC, SH, out);
}

// Round 9
// 740.476 us; speedup vs baseline: 1.6887x; 1.6887x over previous
//
#include <hip/hip_runtime.h>
#include <hip/hip_bf16.h>

// ============================================================================
// HWNet-SPP forward, MFMA bf16 implicit-GEMM with selective hi/lo precision.
// LDS-staged GEMM (global_load_lds, st-swizzled). BM=256 tile for the 1-pass
// heavyweights (conv2/conv4) -> 2x MFMA per barrier; BM=128 elsewhere.
// Pass config per layer (error budget vs absmax threshold 0.098):
//   conv2: Ah*Bh                (1-pass)   conv3: Ah*Bh + Al*Bh  (2-pass)
//   conv4: Ah*Bh                (1-pass)   conv5: full 3-pass hi/lo
//   FC1/FC2: Ah*Bh + Al*Bh      (2-pass)
// BN column stats fused into GEMM epilogue (SPLIT==1) or split-K reducer.
// Conv/FC biases skipped (BN mean-subtraction cancels them exactly).
// ============================================================================

typedef __bf16 bf16;
using bf16x4 = __attribute__((ext_vector_type(4))) __bf16;
using bf16x8 = __attribute__((ext_vector_type(8))) __bf16;
using f32x4  = __attribute__((ext_vector_type(4))) float;

__device__ __forceinline__ void split2(float v, bf16& h, bf16& l) {
  bf16 hb = (bf16)v;
  h = hb;
  l = (bf16)(v - (float)hb);
}

__device__ __forceinline__ void gld_lds16(const bf16* g, void* lds) {
  __builtin_amdgcn_global_load_lds(
      (const __attribute__((address_space(1))) unsigned int*)g,
      (__attribute__((address_space(3))) unsigned int*)lds, 16, 0, 0);
}

// ---------------- pad (edge mode, +2 each side of 48x128) ----------------
__global__ __launch_bounds__(256) void pad_edge_k(const float* __restrict__ x,
                                                  float* __restrict__ p) {
  int i = blockIdx.x * 256 + threadIdx.x;
  const int TOT = 64 * 52 * 132;
  if (i >= TOT) return;
  int w = i % 132; int t = i / 132; int h = t % 52; int n = t / 52;
  int sh = h - 2; sh = sh < 0 ? 0 : (sh > 47 ? 47 : sh);
  int sw = w - 2; sw = sw < 0 ? 0 : (sw > 127 ? 127 : sw);
  p[i] = x[(n * 48 + sh) * 128 + sw];
}

// ---------------- conv1 pass 1: BN stats only (fp32, recompute style) ------
__global__ __launch_bounds__(256) void conv1_stats_k(const float* __restrict__ P,
                                                     const float* __restrict__ wt,
                                                     float* __restrict__ part) {
  int co0 = blockIdx.y * 8;
  float sums[8] = {0.f}, sqs[8] = {0.f};
  for (int r = 0; r < 16; r++) {
    int pix = blockIdx.x * 4096 + r * 256 + threadIdx.x;  // 0..393215
    int w = pix & 127; int t = pix >> 7; int h = t % 48; int n = t / 48;
    const float* ip = P + ((size_t)n * 52 + h) * 132 + w;
    float win[25];
#pragma unroll
    for (int kh = 0; kh < 5; kh++)
#pragma unroll
      for (int kw = 0; kw < 5; kw++) win[kh * 5 + kw] = ip[kh * 132 + kw];
#pragma unroll
    for (int j = 0; j < 8; j++) {
      const float* wp = wt + (size_t)(co0 + j) * 25;
      float acc = 0.f;
#pragma unroll
      for (int k = 0; k < 25; k++) acc += win[k] * wp[k];
      sums[j] += acc; sqs[j] += acc * acc;
    }
  }
  __shared__ float ls[256], lq[256];
  for (int j = 0; j < 8; j++) {
    ls[threadIdx.x] = sums[j]; lq[threadIdx.x] = sqs[j];
    __syncthreads();
    for (int o = 128; o > 0; o >>= 1) {
      if (threadIdx.x < o) { ls[threadIdx.x] += ls[threadIdx.x + o]; lq[threadIdx.x] += lq[threadIdx.x + o]; }
      __syncthreads();
    }
    if (threadIdx.x == 0) {
      int c = co0 + j;
      part[((size_t)c * 96 + blockIdx.x) * 2 + 0] = ls[0];
      part[((size_t)c * 96 + blockIdx.x) * 2 + 1] = lq[0];
    }
    __syncthreads();
  }
}

// ---------------- conv1 pass 2: conv+BN+ReLU+pool+pad -> hi/lo -------------
__global__ __launch_bounds__(256) void conv1_apply_k(const float* __restrict__ P,
                                                     const float* __restrict__ wt,
                                                     const float* __restrict__ scale,
                                                     const float* __restrict__ shift,
                                                     bf16* __restrict__ yh,
                                                     bf16* __restrict__ yl) {
  int pix = blockIdx.x * 256 + threadIdx.x;  // 0..98303
  int ow = pix & 63; int t = pix >> 6; int oh = t % 24; int n = t / 24;
  int co0 = blockIdx.y * 8;
  const float* ip = P + ((size_t)n * 52 + 2 * oh) * 132 + 2 * ow;
  float win[36];
#pragma unroll
  for (int r = 0; r < 6; r++)
#pragma unroll
    for (int c = 0; c < 6; c++) win[r * 6 + c] = ip[r * 132 + c];
  bf16x8 hv, lv;
#pragma unroll
  for (int j = 0; j < 8; j++) {
    const float* wp = wt + (size_t)(co0 + j) * 25;
    float sc = scale[co0 + j], sh = shift[co0 + j];
    float m = -1e30f;
#pragma unroll
    for (int dy = 0; dy < 2; dy++)
#pragma unroll
      for (int dx = 0; dx < 2; dx++) {
        float acc = 0.f;
#pragma unroll
        for (int kh = 0; kh < 5; kh++)
#pragma unroll
          for (int kw = 0; kw < 5; kw++)
            acc += win[(kh + dy) * 6 + kw + dx] * wp[kh * 5 + kw];
        m = fmaxf(m, acc * sc + sh);
      }
    float v = fmaxf(m, 0.f);
    bf16 h, l; split2(v, h, l);
    hv[j] = h; lv[j] = l;
  }
  size_t o = (((size_t)n * 28 + oh + 2) * 68 + ow + 2) * 64 + co0;
  *(bf16x8*)(yh + o) = hv;
  *(bf16x8*)(yl + o) = lv;
}

// ---------------- MFMA implicit-GEMM, selective hi/lo, optional split-K ----
// C[m,co] = Ah.Bh (+ Al.Bh if ALO) (+ Ah.Bl if BLO)
// A from padded NHWC bf16 [64][OH+KS-1][OW+KS-1][CI]; FC: KS=1,OH=OW=2.
// Tile BMx128, BK=64, 4 waves. BM=128: wave-tile 64x64 (2x2 wave grid);
// BM=256: wave-tile 128x64 (2 M-waves x 2 N-waves, 8 m-frags).
// st-swizzle via pre-swizzled global source addresses; global_load_lds 16B.
template<int CI, int KS, int OH, int OW, int CO, bool ALO, bool BLO, int SPLIT, int BM>
__global__ __launch_bounds__(256) void conv_gemm_k(const bf16* __restrict__ Ahi,
                                                   const bf16* __restrict__ Alo,
                                                   const bf16* __restrict__ Bhi,
                                                   const bf16* __restrict__ Blo,
                                                   float* __restrict__ Cout,
                                                   float* __restrict__ part) {
  static_assert(CI % 64 == 0, "chunk must not straddle ci segments");
  constexpr int K = KS * KS * CI;
  constexpr int IWP = OW + KS - 1;
  constexpr int NCH = K / 64;
  static_assert(NCH % SPLIT == 0, "split must divide chunk count");
  constexpr int NCHS = NCH / SPLIT;
  constexpr int M = 64 * OH * OW;
  static_assert(M % BM == 0, "BM must divide M");
  constexpr int MF = BM / 32;       // m-fragments per wave
  constexpr int AISS = BM / 32;     // A staging issues per thread
  __shared__ bf16 Ash[BM * 64];
  __shared__ bf16 Asl[ALO ? BM * 64 : 64];
  __shared__ bf16 Bsh[128 * 64];
  __shared__ bf16 Bsl[BLO ? 128 * 64 : 64];
  __shared__ float red[2][128][8];
  const int t = threadIdx.x;
  const int lane = t & 63, w = t >> 6;
  const int m0 = blockIdx.x * BM, n0 = blockIdx.y * 128;
  const int z = (SPLIT > 1) ? blockIdx.z : 0;

  // staging source precompute (st-swizzle applied on the global source addr)
  int apix[AISS]; size_t boff[4];
#pragma unroll
  for (int i = 0; i < AISS; i++) {
    int f = (i * 4 + w) * 64 + lane;
    int row = f >> 3, slot = f & 7;
    int ss = slot ^ (row & 7);
    int m = m0 + row;
    int n = m / (OH * OW); int rem = m % (OH * OW);
    int oh = rem / OW, ow_ = rem % OW;
    apix[i] = ((n * (OH + KS - 1) + oh) * IWP + ow_) * CI + ss * 8;
  }
#pragma unroll
  for (int i = 0; i < 4; i++) {
    int f = (i * 4 + w) * 64 + lane;
    int row = f >> 3, slot = f & 7;
    int ss = slot ^ (row & 7);
    boff[i] = (size_t)(n0 + row) * K + ss * 8;
  }

  // ds_read fragment addresses
  const int wrow = w >> 1, wcol = w & 1;
  const int kg = lane >> 4, l15 = lane & 15;
  int arb[MF], amk[MF], brb[4], bmk[4];
#pragma unroll
  for (int q = 0; q < MF; q++) {
    int ra = wrow * (BM / 2) + q * 16 + l15;
    arb[q] = ra * 128; amk[q] = ra & 7;
  }
#pragma unroll
  for (int q = 0; q < 4; q++) {
    int rb = wcol * 64 + q * 16 + l15;
    brb[q] = rb * 128; bmk[q] = rb & 7;
  }
  const char* Ashb = (const char*)Ash;
  const char* Aslb = (const char*)Asl;
  const char* Bshb = (const char*)Bsh;
  const char* Bslb = (const char*)Bsl;

  f32x4 acc[MF][4] = {};
  for (int kc = z * NCHS; kc < (z + 1) * NCHS; ++kc) {
    const int k0 = kc * 64;
    const int seg = k0 / CI;
    const int ci0 = k0 % CI;
    const int kh = seg / KS, kw = seg % KS;
    const int aoff = (kh * IWP + kw) * CI + ci0;   // wave-uniform
#pragma unroll
    for (int i = 0; i < AISS; i++) {
      gld_lds16(Ahi + (size_t)apix[i] + aoff, (char*)Ash + (i * 4 + w) * 1024);
      if (ALO)
        gld_lds16(Alo + (size_t)apix[i] + aoff, (char*)Asl + (i * 4 + w) * 1024);
    }
#pragma unroll
    for (int i = 0; i < 4; i++) {
      gld_lds16(Bhi + boff[i] + k0,   (char*)Bsh + (i * 4 + w) * 1024);
      if (BLO)
        gld_lds16(Blo + boff[i] + k0, (char*)Bsl + (i * 4 + w) * 1024);
    }
    __syncthreads();
#pragma unroll
    for (int ks = 0; ks < 2; ks++) {
      const int slot = ks * 4 + kg;
      bf16x8 ah[MF], bh[4];
#pragma unroll
      for (int q = 0; q < MF; q++)
        ah[q] = *(const bf16x8*)(Ashb + arb[q] + ((slot ^ amk[q]) << 4));
#pragma unroll
      for (int q = 0; q < 4; q++)
        bh[q] = *(const bf16x8*)(Bshb + brb[q] + ((slot ^ bmk[q]) << 4));
#pragma unroll
      for (int mi = 0; mi < MF; mi++)
#pragma unroll
        for (int ni = 0; ni < 4; ni++)
          acc[mi][ni] = __builtin_amdgcn_mfma_f32_16x16x32_bf16(ah[mi], bh[ni], acc[mi][ni], 0, 0, 0);
      if (ALO) {
        bf16x8 al[MF];
#pragma unroll
        for (int q = 0; q < MF; q++)
          al[q] = *(const bf16x8*)(Aslb + arb[q] + ((slot ^ amk[q]) << 4));
#pragma unroll
        for (int mi = 0; mi < MF; mi++)
#pragma unroll
          for (int ni = 0; ni < 4; ni++)
            acc[mi][ni] = __builtin_amdgcn_mfma_f32_16x16x32_bf16(al[mi], bh[ni], acc[mi][ni], 0, 0, 0);
      }
      if (BLO) {
        bf16x8 bl[4];
#pragma unroll
        for (int q = 0; q < 4; q++)
          bl[q] = *(const bf16x8*)(Bslb + brb[q] + ((slot ^ bmk[q]) << 4));
#pragma unroll
        for (int mi = 0; mi < MF; mi++)
#pragma unroll
          for (int ni = 0; ni < 4; ni++)
            acc[mi][ni] = __builtin_amdgcn_mfma_f32_16x16x32_bf16(ah[mi], bl[ni], acc[mi][ni], 0, 0, 0);
      }
    }
    __syncthreads();
  }

  // epilogue: D row = (lane>>4)*4 + jj, col = lane&15
  const int crow0 = kg * 4, ccol = l15;
  float* Cz = Cout + (size_t)z * M * CO;
#pragma unroll
  for (int mi = 0; mi < MF; mi++) {
    int m = m0 + wrow * (BM / 2) + mi * 16 + crow0;
#pragma unroll
    for (int ni = 0; ni < 4; ni++) {
      int nn = n0 + wcol * 64 + ni * 16 + ccol;
      float* cp = Cz + (size_t)m * CO + nn;
#pragma unroll
      for (int jj = 0; jj < 4; jj++) cp[(size_t)jj * CO] = acc[mi][ni][jj];
    }
  }
  if constexpr (SPLIT == 1) {
    // fused BN partials: per-thread per-column sums over its MF*4 rows
    const int contrib = kg * 2 + wrow;  // 8 contributors per column
#pragma unroll
    for (int ni = 0; ni < 4; ni++) {
      float s = 0.f, q = 0.f;
#pragma unroll
      for (int mi = 0; mi < MF; mi++)
#pragma unroll
        for (int jj = 0; jj < 4; jj++) {
          float v = acc[mi][ni][jj];
          s += v; q += v * v;
        }
      int coll = wcol * 64 + ni * 16 + ccol;
      red[0][coll][contrib] = s;
      red[1][coll][contrib] = q;
    }
    __syncthreads();
    if (t < 128) {
      float s = 0.f, q = 0.f;
#pragma unroll
      for (int j = 0; j < 8; j++) { s += red[0][t][j]; q += red[1][t][j]; }
      size_t c = n0 + t;
      part[(c * gridDim.x + blockIdx.x) * 2 + 0] = s;
      part[(c * gridDim.x + blockIdx.x) * 2 + 1] = q;
    }
  }
}

// ---------------- split-K reduction + BN partials ----------------
template<int M, int CO, int SPLIT, int NS>
__global__ __launch_bounds__(256) void reduce_bn_k(const float* __restrict__ Cp,
                                                   float* __restrict__ Cf,
                                                   float* __restrict__ part) {
  int c = blockIdx.x * 64 + (threadIdx.x & 63);
  int rl = threadIdx.x >> 6;
  constexpr int ROWS = M / NS;
  int r0 = blockIdx.y * ROWS;
  float sum = 0.f, sq = 0.f;
  for (int r = r0 + rl; r < r0 + ROWS; r += 4) {
    float v = 0.f;
#pragma unroll
    for (int s = 0; s < SPLIT; s++) v += Cp[(size_t)s * M * CO + (size_t)r * CO + c];
    Cf[(size_t)r * CO + c] = v;
    sum += v; sq += v * v;
  }
  __shared__ float ls[256], lq[256];
  ls[threadIdx.x] = sum; lq[threadIdx.x] = sq;
  __syncthreads();
  if (threadIdx.x < 64) {
    sum = ls[threadIdx.x] + ls[threadIdx.x + 64] + ls[threadIdx.x + 128] + ls[threadIdx.x + 192];
    sq  = lq[threadIdx.x] + lq[threadIdx.x + 64] + lq[threadIdx.x + 128] + lq[threadIdx.x + 192];
    part[((size_t)c * NS + blockIdx.y) * 2 + 0] = sum;
    part[((size_t)c * NS + blockIdx.y) * 2 + 1] = sq;
  }
}

__global__ void bn_finalize(const float* __restrict__ part,
                            const float* __restrict__ g, const float* __restrict__ b,
                            float* __restrict__ scale, float* __restrict__ shift,
                            int C, int S, float invCount) {
  int c = blockIdx.x * blockDim.x + threadIdx.x;
  if (c >= C) return;
  float sum = 0.f, sq = 0.f;
  for (int s = 0; s < S; s++) { sum += part[((size_t)c * S + s) * 2]; sq += part[((size_t)c * S + s) * 2 + 1]; }
  float m = sum * invCount;
  float var = sq * invCount - m * m;
  float sc = g[c] * rsqrtf(var + 1e-5f);
  scale[c] = sc;
  shift[c] = b[c] - m * sc;
}

// ---------------- fused BN + ReLU (+2x2 pool) + pad, fp32 -> hi/lo ---------
// Index space covers the PADDED output; halo lanes write zeros (no memset).
template<int CO, int IH, int IW, bool POOL, int PADO>
__global__ __launch_bounds__(256) void bn_act_pad_k(const float* __restrict__ x,
                                                    const float* __restrict__ scale,
                                                    const float* __restrict__ shift,
                                                    bf16* __restrict__ yh,
                                                    bf16* __restrict__ yl) {
  constexpr int OH2 = POOL ? IH / 2 : IH, OW2 = POOL ? IW / 2 : IW;
  constexpr int OHP = OH2 + 2 * PADO, OWP = OW2 + 2 * PADO;
  int i = blockIdx.x * 256 + threadIdx.x;
  if (i >= 64 * OHP * OWP * CO) return;
  int c = i % CO; int t = i / CO; int owp = t % OWP; t /= OWP; int ohp = t % OHP; int n = t / OHP;
  int oh = ohp - PADO, ow = owp - PADO;
  float v = 0.f;
  if (oh >= 0 && oh < OH2 && ow >= 0 && ow < OW2) {
    float sc = scale[c], sh = shift[c];
    if (POOL) {
      const float* p = x + (((size_t)(n * IH) + oh * 2) * IW + ow * 2) * CO + c;
      float a = p[0] * sc + sh;
      float b2 = p[CO] * sc + sh;
      float d = p[(size_t)IW * CO] * sc + sh;
      float e = p[(size_t)(IW + 1) * CO] * sc + sh;
      v = fmaxf(fmaxf(a, b2), fmaxf(d, e));
    } else {
      v = x[(((size_t)(n * OH2) + oh) * OW2 + ow) * CO + c] * sc + sh;
    }
    v = fmaxf(v, 0.f);
  }
  bf16 h, l; split2(v, h, l);
  yh[i] = h; yl[i] = l;
}

// ---------------- ROI SPP: feat hi/lo [64][6][16][512] -> S hi/lo ----------
__global__ __launch_bounds__(256) void spp_k(const bf16* __restrict__ fh,
                                             const bf16* __restrict__ fl,
                                             const int* __restrict__ roi,
                                             bf16* __restrict__ oh_,
                                             bf16* __restrict__ ol_) {
  int c = blockIdx.x * 256 + threadIdx.x;  // 0..511
  int r = blockIdx.y;                      // 0..255
  const int* rp = roi + r * 5;
  int im = rp[0];
  int c1 = rp[1] >> 3, r1 = rp[2] >> 3, c2 = rp[3] >> 3, r2 = rp[4] >> 3;
  int w = c2 - c1 + 1;
  int lo[6], hi[6];
  int bi = 0;
#pragma unroll
  for (int l = 1; l <= 3; l++)
    for (int k = 0; k < l; k++) {
      lo[bi] = c1 + (k * w) / l;
      hi[bi] = c1 + ((k + 1) * w + l - 1) / l - 1;
      bi++;
    }
  float mx[6];
#pragma unroll
  for (int b = 0; b < 6; b++) mx[b] = -1e30f;
  const bf16* ph = fh + (size_t)im * 96 * 512 + c;
  const bf16* pl = fl + (size_t)im * 96 * 512 + c;
  for (int row = r1; row <= r2; row++)
    for (int col = c1; col <= c2; col++) {
      size_t off = (size_t)(row * 16 + col) * 512;
      float v = (float)ph[off] + (float)pl[off];
#pragma unroll
      for (int b = 0; b < 6; b++)
        if (col >= lo[b] && col <= hi[b]) mx[b] = fmaxf(mx[b], v);
    }
  int idx[6] = {c, 512 + c * 2, 512 + c * 2 + 1, 1536 + c * 3, 1536 + c * 3 + 1, 1536 + c * 3 + 2};
#pragma unroll
  for (int b = 0; b < 6; b++) {
    bf16 h, l; split2(mx[b], h, l);
    oh_[(size_t)r * 3072 + idx[b]] = h;
    ol_[(size_t)r * 3072 + idx[b]] = l;
  }
}

// FC1: BN+ReLU, write hi/lo into CC[:, 0:2048] (ld 8192)
__global__ __launch_bounds__(256) void bn1d_apply_cc_k(const float* __restrict__ x,
                                                       const float* __restrict__ scale,
                                                       const float* __restrict__ shift,
                                                       bf16* __restrict__ ch,
                                                       bf16* __restrict__ cl) {
  int i = blockIdx.x * 256 + threadIdx.x;
  if (i >= 256 * 2048) return;
  int f = i & 2047, r = i >> 11;
  float v = fmaxf(x[i] * scale[f] + shift[f], 0.f);
  bf16 h, l; split2(v, h, l);
  ch[(size_t)r * 8192 + f] = h;
  cl[(size_t)r * 8192 + f] = l;
}

// FC2: BN+ReLU, fp32 out
__global__ __launch_bounds__(256) void bn1d_apply_f32_k(const float* __restrict__ x,
                                                        const float* __restrict__ scale,
                                                        const float* __restrict__ shift,
                                                        float* __restrict__ y) {
  int i = blockIdx.x * 256 + threadIdx.x;
  if (i >= 256 * 2048) return;
  int f = i & 2047;
  y[i] = fmaxf(x[i] * scale[f] + shift[f], 0.f);
}

// ---------------- weight transforms ----------------
template<int CI, int CO, int KS>
__global__ __launch_bounds__(256) void wconv_k(const float* __restrict__ w,
                                               bf16* __restrict__ oh_,
                                               bf16* __restrict__ ol_) {
  int i = blockIdx.x * 256 + threadIdx.x;
  if (i >= CO * KS * KS * CI) return;
  int ci = i % CI; int t = i / CI; int kw = t % KS; t /= KS; int kh = t % KS; int co = t / KS;
  float v = w[(((size_t)co * CI + ci) * KS + kh) * KS + kw];
  bf16 h, l; split2(v, h, l);
  oh_[i] = h;
  if (ol_) ol_[i] = l;
}

// fp32 -> bf16 cast, 4 elems/thread (n multiple of 4)
__global__ __launch_bounds__(256) void cast_k(const float* __restrict__ x,
                                              bf16* __restrict__ y, int n4) {
  int i = blockIdx.x * 256 + threadIdx.x;
  if (i >= n4) return;
  const float4 v = *(const float4*)(x + (size_t)i * 4);
  bf16x4 o = { (bf16)v.x, (bf16)v.y, (bf16)v.z, (bf16)v.w };
  *(bf16x4*)(y + (size_t)i * 4) = o;
}

// f2w [2048][7901] fp32 -> [2048][8192] bf16 hi (zero tail), 4 elems/thread
__global__ __launch_bounds__(256) void wfc2_k(const float* __restrict__ x,
                                              bf16* __restrict__ y) {
  int i = blockIdx.x * 256 + threadIdx.x;
  if (i >= 2048 * 2048) return;
  int k = (i & 2047) * 4, n = i >> 11;
  const float* xp = x + (size_t)n * 7901 + k;
  bf16x4 o;
#pragma unroll
  for (int j = 0; j < 4; j++) o[j] = (bf16)((k + j < 7901) ? xp[j] : 0.f);
  *(bf16x4*)(y + (size_t)n * 8192 + k) = o;
}

// phoc [256][5853] fp32 -> CC[:, 2048:8192] hi/lo (zero tail cols)
__global__ __launch_bounds__(256) void phoc_cc_k(const float* __restrict__ phoc,
                                                 bf16* __restrict__ ch,
                                                 bf16* __restrict__ cl) {
  int i = blockIdx.x * 256 + threadIdx.x;
  if (i >= 256 * 6144) return;
  int k = i % 6144, r = i / 6144;
  int col = 2048 + k;
  float v = (col < 7901) ? phoc[(size_t)r * 5853 + (col - 2048)] : 0.f;
  bf16 h, l; split2(v, h, l);
  ch[(size_t)r * 8192 + col] = h;
  cl[(size_t)r * 8192 + col] = l;
}

// ============================================================================
extern "C" void kernel_launch(void* const* d_in, const int* in_sizes, int n_in,
                              void* d_out, int out_size, void* d_ws, size_t ws_size,
                              hipStream_t stream) {
  (void)in_sizes; (void)n_in; (void)out_size; (void)ws_size;

  const float* x    = (const float*)d_in[0];
  const int*   roi  = (const int*)  d_in[1];
  const float* phoc = (const float*)d_in[2];
  const float* c1w  = (const float*)d_in[3];
  const float* g1   = (const float*)d_in[5];
  const float* b1   = (const float*)d_in[6];
  const float* c2w  = (const float*)d_in[7];
  const float* g2   = (const float*)d_in[9];
  const float* b2   = (const float*)d_in[10];
  const float* c3w  = (const float*)d_in[11];
  const float* g3   = (const float*)d_in[13];
  const float* b3   = (const float*)d_in[14];
  const float* c4w  = (const float*)d_in[15];
  const float* g4   = (const float*)d_in[17];
  const float* b4   = (const float*)d_in[18];
  const float* c5w  = (const float*)d_in[19];
  const float* g5   = (const float*)d_in[21];
  const float* b5   = (const float*)d_in[22];
  const float* f1w  = (const float*)d_in[23];
  const float* g6   = (const float*)d_in[25];
  const float* b6   = (const float*)d_in[26];
  const float* f2w  = (const float*)d_in[27];
  const float* g7   = (const float*)d_in[29];
  const float* b7   = (const float*)d_in[30];
  float* out = (float*)d_out;

  // ---- workspace layout (total ~168.4 MB) ----
  char* ws = (char*)d_ws;
  float* P    = (float*)(ws + 0x0000000);   // 1.76 MB
  bf16*  Ahi  = (bf16*) (ws + 0x0200000);   // 16 MB
  bf16*  Alo  = (bf16*) (ws + 0x1200000);   // 16 MB
  float* C    = (float*)(ws + 0x2200000);   // 51 MB region (GEMM out / split slabs)
  float* C5F  = (float*)(ws + 0x4200000);   // conv5 final (32MB into C region)
  bf16*  Wc2h = (bf16*) (ws + 0x5500000);
  bf16*  Wc3h = (bf16*) (ws + 0x5570000);
  bf16*  Wc4h = (bf16*) (ws + 0x5600000);
  bf16*  Wc5h = (bf16*) (ws + 0x5840000);
  bf16*  Wf1  = (bf16*) (ws + 0x5CC0000);
  bf16*  Wf2  = (bf16*) (ws + 0x68C0000);   // [2048][8192] = 32 MB
  bf16*  Wc5l = (bf16*) (ws + 0x8C00000);
  bf16*  Shi  = (bf16*) (ws + 0x9080000);   // spp out hi [256][3072]
  bf16*  Slo  = (bf16*) (ws + 0x9200000);
  float* G6   = (float*)(ws + 0x9380000);   // fc1 out fp32 [256][2048]
  bf16*  CChi = (bf16*) (ws + 0x9580000);   // concat hi [256][8192] = 4 MB
  bf16*  CClo = (bf16*) (ws + 0x9980000);
  float* G7   = (float*)(ws + 0x9D80000);   // fc2 out fp32 [256][2048]
  float* PART = (float*)(ws + 0x9F80000);   // 768 KB
  float* SC   = (float*)(ws + 0xA040000);
  float* SH   = (float*)(ws + 0xA050000);

  // ---- weight transforms ----
  wconv_k<64, 128, 5><<<800, 256, 0, stream>>>(c2w, Wc2h, nullptr);
  wconv_k<128, 256, 3><<<1152, 256, 0, stream>>>(c3w, Wc3h, nullptr);
  wconv_k<256, 512, 3><<<4608, 256, 0, stream>>>(c4w, Wc4h, nullptr);
  wconv_k<512, 512, 3><<<9216, 256, 0, stream>>>(c5w, Wc5h, Wc5l);
  cast_k<<<6144, 256, 0, stream>>>(f1w, Wf1, 2048 * 3072 / 4);
  wfc2_k<<<16384, 256, 0, stream>>>(f2w, Wf2);
  phoc_cc_k<<<6144, 256, 0, stream>>>(phoc, CChi, CClo);

  // ---- conv1 (two-pass, no big fp32 buffer) ----
  pad_edge_k<<<1716, 256, 0, stream>>>(x, P);
  conv1_stats_k<<<dim3(96, 8), 256, 0, stream>>>(P, c1w, PART);
  bn_finalize<<<1, 64, 0, stream>>>(PART, g1, b1, SC, SH, 64, 96, 1.f / 393216.f);
  hipMemsetAsync(Ahi, 0, (size_t)64 * 28 * 68 * 64 * 2, stream);
  hipMemsetAsync(Alo, 0, (size_t)64 * 28 * 68 * 64 * 2, stream);
  conv1_apply_k<<<dim3(384, 8), 256, 0, stream>>>(P, c1w, SC, SH, Ahi, Alo);

  // ---- conv2 (1-pass, BM=256): A[98304][1600] -> C[98304][128] ----
  conv_gemm_k<64, 5, 24, 64, 128, false, false, 1, 256><<<dim3(384, 1), 256, 0, stream>>>(Ahi, Alo, Wc2h, nullptr, C, PART);
  bn_finalize<<<1, 128, 0, stream>>>(PART, g2, b2, SC, SH, 128, 384, 1.f / 98304.f);
  bn_act_pad_k<128, 24, 64, true, 1><<<15232, 256, 0, stream>>>(C, SC, SH, Ahi, Alo);

  // ---- conv3 (2-pass: Ah.Bh + Al.Bh, BM=128) ----
  conv_gemm_k<128, 3, 12, 32, 256, true, false, 1, 128><<<dim3(192, 2), 256, 0, stream>>>(Ahi, Alo, Wc3h, nullptr, C, PART);
  bn_finalize<<<1, 256, 0, stream>>>(PART, g3, b3, SC, SH, 256, 192, 1.f / 24576.f);
  bn_act_pad_k<256, 12, 32, false, 1><<<30464, 256, 0, stream>>>(C, SC, SH, Ahi, Alo);

  // ---- conv4 (1-pass, BM=256) ----
  conv_gemm_k<256, 3, 12, 32, 512, false, false, 1, 256><<<dim3(96, 4), 256, 0, stream>>>(Ahi, Alo, Wc4h, nullptr, C, PART);
  bn_finalize<<<2, 256, 0, stream>>>(PART, g4, b4, SC, SH, 512, 96, 1.f / 24576.f);
  bn_act_pad_k<512, 12, 32, true, 1><<<18432, 256, 0, stream>>>(C, SC, SH, Ahi, Alo);

  // ---- conv5 (3-pass, split-K=2, BM=128): slabs in C, final in C5F ----
  conv_gemm_k<512, 3, 6, 16, 512, true, true, 2, 128><<<dim3(48, 4, 2), 256, 0, stream>>>(Ahi, Alo, Wc5h, Wc5l, C, nullptr);
  reduce_bn_k<6144, 512, 2, 16><<<dim3(8, 16), 256, 0, stream>>>(C, C5F, PART);
  bn_finalize<<<2, 256, 0, stream>>>(PART, g5, b5, SC, SH, 512, 16, 1.f / 6144.f);
  bn_act_pad_k<512, 6, 16, false, 0><<<12288, 256, 0, stream>>>(C5F, SC, SH, Ahi, Alo);  // feat

  // ---- SPP ----
  spp_k<<<dim3(2, 256), 256, 0, stream>>>(Ahi, Alo, roi, Shi, Slo);

  // ---- FC1 (2-pass, split-K=8, BM=128): [256][3072] x [2048][3072] ----
  conv_gemm_k<3072, 1, 2, 2, 2048, true, false, 8, 128><<<dim3(2, 16, 8), 256, 0, stream>>>(Shi, Slo, Wf1, nullptr, C, nullptr);
  reduce_bn_k<256, 2048, 8, 4><<<dim3(32, 4), 256, 0, stream>>>(C, G6, PART);
  bn_finalize<<<8, 256, 0, stream>>>(PART, g6, b6, SC, SH, 2048, 4, 1.f / 256.f);
  bn1d_apply_cc_k<<<2048, 256, 0, stream>>>(G6, SC, SH, CChi, CClo);

  // ---- FC2 (2-pass, split-K=8, BM=128): [256][8192] x [2048][8192] ----
  conv_gemm_k<8192, 1, 2, 2, 2048, true, false, 8, 128><<<dim3(2, 16, 8), 256, 0, stream>>>(CChi, CClo, Wf2, nullptr, C, nullptr);
  reduce_bn_k<256, 2048, 8, 4><<<dim3(32, 4), 256, 0, stream>>>(C, G7, PART);
  bn_finalize<<<8, 256, 0, stream>>>(PART, g7, b7, SC, SH, 2048, 4, 1.f / 256.f);
  bn1d_apply_f32_k<<<2048, 256, 0, stream>>>(G7, SC, SH, out);
}

// Round 10
// 737.519 us; speedup vs baseline: 1.6954x; 1.0040x over previous
//
#include <hip/hip_runtime.h>
#include <hip/hip_bf16.h>

// ============================================================================
// HWNet-SPP forward, MFMA bf16 implicit-GEMM with selective hi/lo precision.
// conv2 uses a specialized A-RESIDENT kernel: the block's full 5x5 receptive
// field (6 rows x 68 x 64ch = 51KB) is staged to LDS once; the K-loop only
// streams B. Other layers use the proven 128x128 streaming template.
// Pass config per layer (error budget vs absmax threshold 0.098):
//   conv2: Ah*Bh                (1-pass)   conv3: Ah*Bh + Al*Bh  (2-pass)
//   conv4: Ah*Bh                (1-pass)   conv5: full 3-pass hi/lo
//   FC1/FC2: Ah*Bh + Al*Bh      (2-pass)
// BN column stats fused into GEMM epilogue (SPLIT==1) or split-K reducer.
// Conv/FC biases skipped (BN mean-subtraction cancels them exactly).
// ============================================================================

typedef __bf16 bf16;
using bf16x4 = __attribute__((ext_vector_type(4))) __bf16;
using bf16x8 = __attribute__((ext_vector_type(8))) __bf16;
using f32x4  = __attribute__((ext_vector_type(4))) float;

__device__ __forceinline__ void split2(float v, bf16& h, bf16& l) {
  bf16 hb = (bf16)v;
  h = hb;
  l = (bf16)(v - (float)hb);
}

__device__ __forceinline__ void gld_lds16(const bf16* g, void* lds) {
  __builtin_amdgcn_global_load_lds(
      (const __attribute__((address_space(1))) unsigned int*)g,
      (__attribute__((address_space(3))) unsigned int*)lds, 16, 0, 0);
}

// ---------------- pad (edge mode, +2 each side of 48x128) ----------------
__global__ __launch_bounds__(256) void pad_edge_k(const float* __restrict__ x,
                                                  float* __restrict__ p) {
  int i = blockIdx.x * 256 + threadIdx.x;
  const int TOT = 64 * 52 * 132;
  if (i >= TOT) return;
  int w = i % 132; int t = i / 132; int h = t % 52; int n = t / 52;
  int sh = h - 2; sh = sh < 0 ? 0 : (sh > 47 ? 47 : sh);
  int sw = w - 2; sw = sw < 0 ? 0 : (sw > 127 ? 127 : sw);
  p[i] = x[(n * 48 + sh) * 128 + sw];
}

// ---------------- conv1 pass 1: BN stats only (fp32, recompute style) ------
__global__ __launch_bounds__(256) void conv1_stats_k(const float* __restrict__ P,
                                                     const float* __restrict__ wt,
                                                     float* __restrict__ part) {
  int co0 = blockIdx.y * 8;
  float sums[8] = {0.f}, sqs[8] = {0.f};
  for (int r = 0; r < 16; r++) {
    int pix = blockIdx.x * 4096 + r * 256 + threadIdx.x;  // 0..393215
    int w = pix & 127; int t = pix >> 7; int h = t % 48; int n = t / 48;
    const float* ip = P + ((size_t)n * 52 + h) * 132 + w;
    float win[25];
#pragma unroll
    for (int kh = 0; kh < 5; kh++)
#pragma unroll
      for (int kw = 0; kw < 5; kw++) win[kh * 5 + kw] = ip[kh * 132 + kw];
#pragma unroll
    for (int j = 0; j < 8; j++) {
      const float* wp = wt + (size_t)(co0 + j) * 25;
      float acc = 0.f;
#pragma unroll
      for (int k = 0; k < 25; k++) acc += win[k] * wp[k];
      sums[j] += acc; sqs[j] += acc * acc;
    }
  }
  __shared__ float ls[256], lq[256];
  for (int j = 0; j < 8; j++) {
    ls[threadIdx.x] = sums[j]; lq[threadIdx.x] = sqs[j];
    __syncthreads();
    for (int o = 128; o > 0; o >>= 1) {
      if (threadIdx.x < o) { ls[threadIdx.x] += ls[threadIdx.x + o]; lq[threadIdx.x] += lq[threadIdx.x + o]; }
      __syncthreads();
    }
    if (threadIdx.x == 0) {
      int c = co0 + j;
      part[((size_t)c * 96 + blockIdx.x) * 2 + 0] = ls[0];
      part[((size_t)c * 96 + blockIdx.x) * 2 + 1] = lq[0];
    }
    __syncthreads();
  }
}

// ---------------- conv1 pass 2: conv+BN+ReLU+pool+pad -> hi/lo -------------
__global__ __launch_bounds__(256) void conv1_apply_k(const float* __restrict__ P,
                                                     const float* __restrict__ wt,
                                                     const float* __restrict__ scale,
                                                     const float* __restrict__ shift,
                                                     bf16* __restrict__ yh,
                                                     bf16* __restrict__ yl) {
  int pix = blockIdx.x * 256 + threadIdx.x;  // 0..98303
  int ow = pix & 63; int t = pix >> 6; int oh = t % 24; int n = t / 24;
  int co0 = blockIdx.y * 8;
  const float* ip = P + ((size_t)n * 52 + 2 * oh) * 132 + 2 * ow;
  float win[36];
#pragma unroll
  for (int r = 0; r < 6; r++)
#pragma unroll
    for (int c = 0; c < 6; c++) win[r * 6 + c] = ip[r * 132 + c];
  bf16x8 hv, lv;
#pragma unroll
  for (int j = 0; j < 8; j++) {
    const float* wp = wt + (size_t)(co0 + j) * 25;
    float sc = scale[co0 + j], sh = shift[co0 + j];
    float m = -1e30f;
#pragma unroll
    for (int dy = 0; dy < 2; dy++)
#pragma unroll
      for (int dx = 0; dx < 2; dx++) {
        float acc = 0.f;
#pragma unroll
        for (int kh = 0; kh < 5; kh++)
#pragma unroll
          for (int kw = 0; kw < 5; kw++)
            acc += win[(kh + dy) * 6 + kw + dx] * wp[kh * 5 + kw];
        m = fmaxf(m, acc * sc + sh);
      }
    float v = fmaxf(m, 0.f);
    bf16 h, l; split2(v, h, l);
    hv[j] = h; lv[j] = l;
  }
  size_t o = (((size_t)n * 28 + oh + 2) * 68 + ow + 2) * 64 + co0;
  *(bf16x8*)(yh + o) = hv;
  *(bf16x8*)(yl + o) = lv;
}

// ---------------- conv2 specialized: A-resident implicit GEMM --------------
// A padded NHWC [64][28][68][64] bf16 hi. Block = 128 output pixels (2 image
// rows x 64 cols) x all 128 output channels. Receptive field (6x68 pixels x
// 64 ch, slot-swizzled) staged once; K-loop (25 chunks) streams only B.
__global__ __launch_bounds__(256) void conv2_gemm_k(const bf16* __restrict__ Ahi,
                                                    const bf16* __restrict__ Bhi,
                                                    float* __restrict__ Cout,
                                                    float* __restrict__ part) {
  __shared__ bf16 Ash[416 * 64];      // 52 KB
  __shared__ bf16 Bsh[128 * 64];      // 16 KB
  __shared__ float red[2][128][8];    // 8 KB
  const int t = threadIdx.x;
  const int lane = t & 63, w = t >> 6;
  const int m0 = blockIdx.x * 128;
  const int img = m0 / 1536;          // 24*64 pixels per image
  const int oh0 = (m0 % 1536) >> 6;   // first of 2 output rows
  const size_t abase = ((size_t)(img * 28 + oh0) * 68) * 64;

  // ---- stage A receptive field (408 pixels x 64ch), slot-swizzled source --
#pragma unroll
  for (int i = 0; i < 13; i++) {
    int f = i * 256 + t;              // slot-linear index 0..3327
    int p = f >> 3; if (p > 407) p = 407;
    int s = f & 7;
    int ss = s ^ (p & 7);
    gld_lds16(Ahi + abase + (size_t)p * 64 + ss * 8,
              (char*)Ash + (size_t)(i * 256 + w * 64) * 16);
  }

  // B staging source offsets (st-swizzled rows)
  size_t boff[4];
#pragma unroll
  for (int i = 0; i < 4; i++) {
    int f = (i * 4 + w) * 64 + lane;
    int row = f >> 3, slot = f & 7;
    int ss = slot ^ (row & 7);
    boff[i] = (size_t)row * 1600 + ss * 8;
  }

  const int wrow = w >> 1, wcol = w & 1;
  const int kg = lane >> 4, l15 = lane & 15;
  int pixb[4];
#pragma unroll
  for (int q = 0; q < 4; q++) pixb[q] = wrow * 68 + q * 16 + l15;
  int brb[4], bmk[4];
#pragma unroll
  for (int q = 0; q < 4; q++) {
    int rb = wcol * 64 + q * 16 + l15;
    brb[q] = rb * 128; bmk[q] = rb & 7;
  }
  const char* Ashb = (const char*)Ash;
  const char* Bshb = (const char*)Bsh;

  f32x4 acc[4][4] = {};
  for (int kc = 0; kc < 25; ++kc) {
    const int kh = kc / 5, kw = kc % 5;
    const int kofs = kh * 68 + kw;    // wave-uniform pixel offset
    const int k0 = kc * 64;
#pragma unroll
    for (int i = 0; i < 4; i++)
      gld_lds16(Bhi + boff[i] + k0, (char*)Bsh + (i * 4 + w) * 1024);
    __syncthreads();                  // drains A (first iter) + this B
#pragma unroll
    for (int ks = 0; ks < 2; ks++) {
      const int slot = ks * 4 + kg;
      bf16x8 ah[4], bh[4];
#pragma unroll
      for (int q = 0; q < 4; q++) {
        int pix = pixb[q] + kofs;
        ah[q] = *(const bf16x8*)(Ashb + pix * 128 + ((slot ^ (pix & 7)) << 4));
        bh[q] = *(const bf16x8*)(Bshb + brb[q] + ((slot ^ bmk[q]) << 4));
      }
#pragma unroll
      for (int mi = 0; mi < 4; mi++)
#pragma unroll
        for (int ni = 0; ni < 4; ni++)
          acc[mi][ni] = __builtin_amdgcn_mfma_f32_16x16x32_bf16(ah[mi], bh[ni], acc[mi][ni], 0, 0, 0);
    }
    __syncthreads();                  // all waves done with Bsh
  }

  // epilogue: D row = (lane>>4)*4 + jj, col = lane&15
  const int crow0 = kg * 4, ccol = l15;
#pragma unroll
  for (int mi = 0; mi < 4; mi++) {
    int m = m0 + wrow * 64 + mi * 16 + crow0;
#pragma unroll
    for (int ni = 0; ni < 4; ni++) {
      int nn = wcol * 64 + ni * 16 + ccol;
      float* cp = Cout + (size_t)m * 128 + nn;
#pragma unroll
      for (int jj = 0; jj < 4; jj++) cp[(size_t)jj * 128] = acc[mi][ni][jj];
    }
  }
  // fused BN partials
  const int contrib = kg * 2 + wrow;
#pragma unroll
  for (int ni = 0; ni < 4; ni++) {
    float s = 0.f, q = 0.f;
#pragma unroll
    for (int mi = 0; mi < 4; mi++)
#pragma unroll
      for (int jj = 0; jj < 4; jj++) {
        float v = acc[mi][ni][jj];
        s += v; q += v * v;
      }
    int coll = wcol * 64 + ni * 16 + ccol;
    red[0][coll][contrib] = s;
    red[1][coll][contrib] = q;
  }
  __syncthreads();
  if (t < 128) {
    float s = 0.f, q = 0.f;
#pragma unroll
    for (int j = 0; j < 8; j++) { s += red[0][t][j]; q += red[1][t][j]; }
    size_t c = t;
    part[(c * gridDim.x + blockIdx.x) * 2 + 0] = s;
    part[(c * gridDim.x + blockIdx.x) * 2 + 1] = q;
  }
}

// ---------------- MFMA implicit-GEMM, selective hi/lo, optional split-K ----
// C[m,co] = Ah.Bh (+ Al.Bh if ALO) (+ Ah.Bl if BLO)
// Tile 128x128, BK=64, 4 waves (2x2 wave grid, wave-tile 64x64).
template<int CI, int KS, int OH, int OW, int CO, bool ALO, bool BLO, int SPLIT>
__global__ __launch_bounds__(256) void conv_gemm_k(const bf16* __restrict__ Ahi,
                                                   const bf16* __restrict__ Alo,
                                                   const bf16* __restrict__ Bhi,
                                                   const bf16* __restrict__ Blo,
                                                   float* __restrict__ Cout,
                                                   float* __restrict__ part) {
  static_assert(CI % 64 == 0, "chunk must not straddle ci segments");
  constexpr int K = KS * KS * CI;
  constexpr int IWP = OW + KS - 1;
  constexpr int NCH = K / 64;
  static_assert(NCH % SPLIT == 0, "split must divide chunk count");
  constexpr int NCHS = NCH / SPLIT;
  constexpr int M = 64 * OH * OW;
  __shared__ bf16 Ash[128 * 64];
  __shared__ bf16 Asl[ALO ? 128 * 64 : 64];
  __shared__ bf16 Bsh[128 * 64];
  __shared__ bf16 Bsl[BLO ? 128 * 64 : 64];
  __shared__ float red[2][128][8];
  const int t = threadIdx.x;
  const int lane = t & 63, w = t >> 6;
  const int m0 = blockIdx.x * 128, n0 = blockIdx.y * 128;
  const int z = (SPLIT > 1) ? blockIdx.z : 0;

  int apix[4]; size_t boff[4];
#pragma unroll
  for (int i = 0; i < 4; i++) {
    int f = (i * 4 + w) * 64 + lane;
    int row = f >> 3, slot = f & 7;
    int ss = slot ^ (row & 7);
    int m = m0 + row;
    int n = m / (OH * OW); int rem = m % (OH * OW);
    int oh = rem / OW, ow_ = rem % OW;
    apix[i] = ((n * (OH + KS - 1) + oh) * IWP + ow_) * CI + ss * 8;
    boff[i] = (size_t)(n0 + row) * K + ss * 8;
  }

  const int wrow = w >> 1, wcol = w & 1;
  const int kg = lane >> 4, l15 = lane & 15;
  int arb[4], amk[4], brb[4], bmk[4];
#pragma unroll
  for (int q = 0; q < 4; q++) {
    int ra = wrow * 64 + q * 16 + l15;
    arb[q] = ra * 128; amk[q] = ra & 7;
    int rb = wcol * 64 + q * 16 + l15;
    brb[q] = rb * 128; bmk[q] = rb & 7;
  }
  const char* Ashb = (const char*)Ash;
  const char* Aslb = (const char*)Asl;
  const char* Bshb = (const char*)Bsh;
  const char* Bslb = (const char*)Bsl;

  f32x4 acc[4][4] = {};
  for (int kc = z * NCHS; kc < (z + 1) * NCHS; ++kc) {
    const int k0 = kc * 64;
    const int seg = k0 / CI;
    const int ci0 = k0 % CI;
    const int kh = seg / KS, kw = seg % KS;
    const int aoff = (kh * IWP + kw) * CI + ci0;   // wave-uniform
#pragma unroll
    for (int i = 0; i < 4; i++) {
      gld_lds16(Ahi + (size_t)apix[i] + aoff, (char*)Ash + (i * 4 + w) * 1024);
      if (ALO)
        gld_lds16(Alo + (size_t)apix[i] + aoff, (char*)Asl + (i * 4 + w) * 1024);
      gld_lds16(Bhi + boff[i] + k0,   (char*)Bsh + (i * 4 + w) * 1024);
      if (BLO)
        gld_lds16(Blo + boff[i] + k0, (char*)Bsl + (i * 4 + w) * 1024);
    }
    __syncthreads();
#pragma unroll
    for (int ks = 0; ks < 2; ks++) {
      const int slot = ks * 4 + kg;
      bf16x8 ah[4], bh[4];
#pragma unroll
      for (int q = 0; q < 4; q++) {
        ah[q] = *(const bf16x8*)(Ashb + arb[q] + ((slot ^ amk[q]) << 4));
        bh[q] = *(const bf16x8*)(Bshb + brb[q] + ((slot ^ bmk[q]) << 4));
      }
#pragma unroll
      for (int mi = 0; mi < 4; mi++)
#pragma unroll
        for (int ni = 0; ni < 4; ni++)
          acc[mi][ni] = __builtin_amdgcn_mfma_f32_16x16x32_bf16(ah[mi], bh[ni], acc[mi][ni], 0, 0, 0);
      if (ALO) {
        bf16x8 al[4];
#pragma unroll
        for (int q = 0; q < 4; q++)
          al[q] = *(const bf16x8*)(Aslb + arb[q] + ((slot ^ amk[q]) << 4));
#pragma unroll
        for (int mi = 0; mi < 4; mi++)
#pragma unroll
          for (int ni = 0; ni < 4; ni++)
            acc[mi][ni] = __builtin_amdgcn_mfma_f32_16x16x32_bf16(al[mi], bh[ni], acc[mi][ni], 0, 0, 0);
      }
      if (BLO) {
        bf16x8 bl[4];
#pragma unroll
        for (int q = 0; q < 4; q++)
          bl[q] = *(const bf16x8*)(Bslb + brb[q] + ((slot ^ bmk[q]) << 4));
#pragma unroll
        for (int mi = 0; mi < 4; mi++)
#pragma unroll
          for (int ni = 0; ni < 4; ni++)
            acc[mi][ni] = __builtin_amdgcn_mfma_f32_16x16x32_bf16(ah[mi], bl[ni], acc[mi][ni], 0, 0, 0);
      }
    }
    __syncthreads();
  }

  const int crow0 = kg * 4, ccol = l15;
  float* Cz = Cout + (size_t)z * M * CO;
#pragma unroll
  for (int mi = 0; mi < 4; mi++) {
    int m = m0 + wrow * 64 + mi * 16 + crow0;
#pragma unroll
    for (int ni = 0; ni < 4; ni++) {
      int nn = n0 + wcol * 64 + ni * 16 + ccol;
      float* cp = Cz + (size_t)m * CO + nn;
#pragma unroll
      for (int jj = 0; jj < 4; jj++) cp[(size_t)jj * CO] = acc[mi][ni][jj];
    }
  }
  if constexpr (SPLIT == 1) {
    const int contrib = kg * 2 + wrow;
#pragma unroll
    for (int ni = 0; ni < 4; ni++) {
      float s = 0.f, q = 0.f;
#pragma unroll
      for (int mi = 0; mi < 4; mi++)
#pragma unroll
        for (int jj = 0; jj < 4; jj++) {
          float v = acc[mi][ni][jj];
          s += v; q += v * v;
        }
      int coll = wcol * 64 + ni * 16 + ccol;
      red[0][coll][contrib] = s;
      red[1][coll][contrib] = q;
    }
    __syncthreads();
    if (t < 128) {
      float s = 0.f, q = 0.f;
#pragma unroll
      for (int j = 0; j < 8; j++) { s += red[0][t][j]; q += red[1][t][j]; }
      size_t c = n0 + t;
      part[(c * gridDim.x + blockIdx.x) * 2 + 0] = s;
      part[(c * gridDim.x + blockIdx.x) * 2 + 1] = q;
    }
  }
}

// ---------------- split-K reduction + BN partials ----------------
template<int M, int CO, int SPLIT, int NS>
__global__ __launch_bounds__(256) void reduce_bn_k(const float* __restrict__ Cp,
                                                   float* __restrict__ Cf,
                                                   float* __restrict__ part) {
  int c = blockIdx.x * 64 + (threadIdx.x & 63);
  int rl = threadIdx.x >> 6;
  constexpr int ROWS = M / NS;
  int r0 = blockIdx.y * ROWS;
  float sum = 0.f, sq = 0.f;
  for (int r = r0 + rl; r < r0 + ROWS; r += 4) {
    float v = 0.f;
#pragma unroll
    for (int s = 0; s < SPLIT; s++) v += Cp[(size_t)s * M * CO + (size_t)r * CO + c];
    Cf[(size_t)r * CO + c] = v;
    sum += v; sq += v * v;
  }
  __shared__ float ls[256], lq[256];
  ls[threadIdx.x] = sum; lq[threadIdx.x] = sq;
  __syncthreads();
  if (threadIdx.x < 64) {
    sum = ls[threadIdx.x] + ls[threadIdx.x + 64] + ls[threadIdx.x + 128] + ls[threadIdx.x + 192];
    sq  = lq[threadIdx.x] + lq[threadIdx.x + 64] + lq[threadIdx.x + 128] + lq[threadIdx.x + 192];
    part[((size_t)c * NS + blockIdx.y) * 2 + 0] = sum;
    part[((size_t)c * NS + blockIdx.y) * 2 + 1] = sq;
  }
}

__global__ void bn_finalize(const float* __restrict__ part,
                            const float* __restrict__ g, const float* __restrict__ b,
                            float* __restrict__ scale, float* __restrict__ shift,
                            int C, int S, float invCount) {
  int c = blockIdx.x * blockDim.x + threadIdx.x;
  if (c >= C) return;
  float sum = 0.f, sq = 0.f;
  for (int s = 0; s < S; s++) { sum += part[((size_t)c * S + s) * 2]; sq += part[((size_t)c * S + s) * 2 + 1]; }
  float m = sum * invCount;
  float var = sq * invCount - m * m;
  float sc = g[c] * rsqrtf(var + 1e-5f);
  scale[c] = sc;
  shift[c] = b[c] - m * sc;
}

// ---------------- fused BN + ReLU (+2x2 pool) + pad, fp32 -> hi/lo ---------
template<int CO, int IH, int IW, bool POOL, int PADO>
__global__ __launch_bounds__(256) void bn_act_pad_k(const float* __restrict__ x,
                                                    const float* __restrict__ scale,
                                                    const float* __restrict__ shift,
                                                    bf16* __restrict__ yh,
                                                    bf16* __restrict__ yl) {
  constexpr int OH2 = POOL ? IH / 2 : IH, OW2 = POOL ? IW / 2 : IW;
  constexpr int OHP = OH2 + 2 * PADO, OWP = OW2 + 2 * PADO;
  int i = blockIdx.x * 256 + threadIdx.x;
  if (i >= 64 * OHP * OWP * CO) return;
  int c = i % CO; int t = i / CO; int owp = t % OWP; t /= OWP; int ohp = t % OHP; int n = t / OHP;
  int oh = ohp - PADO, ow = owp - PADO;
  float v = 0.f;
  if (oh >= 0 && oh < OH2 && ow >= 0 && ow < OW2) {
    float sc = scale[c], sh = shift[c];
    if (POOL) {
      const float* p = x + (((size_t)(n * IH) + oh * 2) * IW + ow * 2) * CO + c;
      float a = p[0] * sc + sh;
      float b2 = p[CO] * sc + sh;
      float d = p[(size_t)IW * CO] * sc + sh;
      float e = p[(size_t)(IW + 1) * CO] * sc + sh;
      v = fmaxf(fmaxf(a, b2), fmaxf(d, e));
    } else {
      v = x[(((size_t)(n * OH2) + oh) * OW2 + ow) * CO + c] * sc + sh;
    }
    v = fmaxf(v, 0.f);
  }
  bf16 h, l; split2(v, h, l);
  yh[i] = h; yl[i] = l;
}

// ---------------- ROI SPP: feat hi/lo [64][6][16][512] -> S hi/lo ----------
__global__ __launch_bounds__(256) void spp_k(const bf16* __restrict__ fh,
                                             const bf16* __restrict__ fl,
                                             const int* __restrict__ roi,
                                             bf16* __restrict__ oh_,
                                             bf16* __restrict__ ol_) {
  int c = blockIdx.x * 256 + threadIdx.x;  // 0..511
  int r = blockIdx.y;                      // 0..255
  const int* rp = roi + r * 5;
  int im = rp[0];
  int c1 = rp[1] >> 3, r1 = rp[2] >> 3, c2 = rp[3] >> 3, r2 = rp[4] >> 3;
  int w = c2 - c1 + 1;
  int lo[6], hi[6];
  int bi = 0;
#pragma unroll
  for (int l = 1; l <= 3; l++)
    for (int k = 0; k < l; k++) {
      lo[bi] = c1 + (k * w) / l;
      hi[bi] = c1 + ((k + 1) * w + l - 1) / l - 1;
      bi++;
    }
  float mx[6];
#pragma unroll
  for (int b = 0; b < 6; b++) mx[b] = -1e30f;
  const bf16* ph = fh + (size_t)im * 96 * 512 + c;
  const bf16* pl = fl + (size_t)im * 96 * 512 + c;
  for (int row = r1; row <= r2; row++)
    for (int col = c1; col <= c2; col++) {
      size_t off = (size_t)(row * 16 + col) * 512;
      float v = (float)ph[off] + (float)pl[off];
#pragma unroll
      for (int b = 0; b < 6; b++)
        if (col >= lo[b] && col <= hi[b]) mx[b] = fmaxf(mx[b], v);
    }
  int idx[6] = {c, 512 + c * 2, 512 + c * 2 + 1, 1536 + c * 3, 1536 + c * 3 + 1, 1536 + c * 3 + 2};
#pragma unroll
  for (int b = 0; b < 6; b++) {
    bf16 h, l; split2(mx[b], h, l);
    oh_[(size_t)r * 3072 + idx[b]] = h;
    ol_[(size_t)r * 3072 + idx[b]] = l;
  }
}

// FC1: BN+ReLU, write hi/lo into CC[:, 0:2048] (ld 8192)
__global__ __launch_bounds__(256) void bn1d_apply_cc_k(const float* __restrict__ x,
                                                       const float* __restrict__ scale,
                                                       const float* __restrict__ shift,
                                                       bf16* __restrict__ ch,
                                                       bf16* __restrict__ cl) {
  int i = blockIdx.x * 256 + threadIdx.x;
  if (i >= 256 * 2048) return;
  int f = i & 2047, r = i >> 11;
  float v = fmaxf(x[i] * scale[f] + shift[f], 0.f);
  bf16 h, l; split2(v, h, l);
  ch[(size_t)r * 8192 + f] = h;
  cl[(size_t)r * 8192 + f] = l;
}

// FC2: BN+ReLU, fp32 out
__global__ __launch_bounds__(256) void bn1d_apply_f32_k(const float* __restrict__ x,
                                                        const float* __restrict__ scale,
                                                        const float* __restrict__ shift,
                                                        float* __restrict__ y) {
  int i = blockIdx.x * 256 + threadIdx.x;
  if (i >= 256 * 2048) return;
  int f = i & 2047;
  y[i] = fmaxf(x[i] * scale[f] + shift[f], 0.f);
}

// ---------------- weight transforms ----------------
template<int CI, int CO, int KS>
__global__ __launch_bounds__(256) void wconv_k(const float* __restrict__ w,
                                               bf16* __restrict__ oh_,
                                               bf16* __restrict__ ol_) {
  int i = blockIdx.x * 256 + threadIdx.x;
  if (i >= CO * KS * KS * CI) return;
  int ci = i % CI; int t = i / CI; int kw = t % KS; t /= KS; int kh = t % KS; int co = t / KS;
  float v = w[(((size_t)co * CI + ci) * KS + kh) * KS + kw];
  bf16 h, l; split2(v, h, l);
  oh_[i] = h;
  if (ol_) ol_[i] = l;
}

// fp32 -> bf16 cast, 4 elems/thread (n multiple of 4)
__global__ __launch_bounds__(256) void cast_k(const float* __restrict__ x,
                                              bf16* __restrict__ y, int n4) {
  int i = blockIdx.x * 256 + threadIdx.x;
  if (i >= n4) return;
  const float4 v = *(const float4*)(x + (size_t)i * 4);
  bf16x4 o = { (bf16)v.x, (bf16)v.y, (bf16)v.z, (bf16)v.w };
  *(bf16x4*)(y + (size_t)i * 4) = o;
}

// f2w [2048][7901] fp32 -> [2048][8192] bf16 hi (zero tail), 4 elems/thread
__global__ __launch_bounds__(256) void wfc2_k(const float* __restrict__ x,
                                              bf16* __restrict__ y) {
  int i = blockIdx.x * 256 + threadIdx.x;
  if (i >= 2048 * 2048) return;
  int k = (i & 2047) * 4, n = i >> 11;
  const float* xp = x + (size_t)n * 7901 + k;
  bf16x4 o;
#pragma unroll
  for (int j = 0; j < 4; j++) o[j] = (bf16)((k + j < 7901) ? xp[j] : 0.f);
  *(bf16x4*)(y + (size_t)n * 8192 + k) = o;
}

// phoc [256][5853] fp32 -> CC[:, 2048:8192] hi/lo (zero tail cols)
__global__ __launch_bounds__(256) void phoc_cc_k(const float* __restrict__ phoc,
                                                 bf16* __restrict__ ch,
                                                 bf16* __restrict__ cl) {
  int i = blockIdx.x * 256 + threadIdx.x;
  if (i >= 256 * 6144) return;
  int k = i % 6144, r = i / 6144;
  int col = 2048 + k;
  float v = (col < 7901) ? phoc[(size_t)r * 5853 + (col - 2048)] : 0.f;
  bf16 h, l; split2(v, h, l);
  ch[(size_t)r * 8192 + col] = h;
  cl[(size_t)r * 8192 + col] = l;
}

// ============================================================================
extern "C" void kernel_launch(void* const* d_in, const int* in_sizes, int n_in,
                              void* d_out, int out_size, void* d_ws, size_t ws_size,
                              hipStream_t stream) {
  (void)in_sizes; (void)n_in; (void)out_size; (void)ws_size;

  const float* x    = (const float*)d_in[0];
  const int*   roi  = (const int*)  d_in[1];
  const float* phoc = (const float*)d_in[2];
  const float* c1w  = (const float*)d_in[3];
  const float* g1   = (const float*)d_in[5];
  const float* b1   = (const float*)d_in[6];
  const float* c2w  = (const float*)d_in[7];
  const float* g2   = (const float*)d_in[9];
  const float* b2   = (const float*)d_in[10];
  const float* c3w  = (const float*)d_in[11];
  const float* g3   = (const float*)d_in[13];
  const float* b3   = (const float*)d_in[14];
  const float* c4w  = (const float*)d_in[15];
  const float* g4   = (const float*)d_in[17];
  const float* b4   = (const float*)d_in[18];
  const float* c5w  = (const float*)d_in[19];
  const float* g5   = (const float*)d_in[21];
  const float* b5   = (const float*)d_in[22];
  const float* f1w  = (const float*)d_in[23];
  const float* g6   = (const float*)d_in[25];
  const float* b6   = (const float*)d_in[26];
  const float* f2w  = (const float*)d_in[27];
  const float* g7   = (const float*)d_in[29];
  const float* b7   = (const float*)d_in[30];
  float* out = (float*)d_out;

  // ---- workspace layout (total ~168.4 MB) ----
  char* ws = (char*)d_ws;
  float* P    = (float*)(ws + 0x0000000);   // 1.76 MB
  bf16*  Ahi  = (bf16*) (ws + 0x0200000);   // 16 MB
  bf16*  Alo  = (bf16*) (ws + 0x1200000);   // 16 MB
  float* C    = (float*)(ws + 0x2200000);   // 51 MB region (GEMM out / split slabs)
  float* C5F  = (float*)(ws + 0x4200000);   // conv5 final (32MB into C region)
  bf16*  Wc2h = (bf16*) (ws + 0x5500000);
  bf16*  Wc3h = (bf16*) (ws + 0x5570000);
  bf16*  Wc4h = (bf16*) (ws + 0x5600000);
  bf16*  Wc5h = (bf16*) (ws + 0x5840000);
  bf16*  Wf1  = (bf16*) (ws + 0x5CC0000);
  bf16*  Wf2  = (bf16*) (ws + 0x68C0000);   // [2048][8192] = 32 MB
  bf16*  Wc5l = (bf16*) (ws + 0x8C00000);
  bf16*  Shi  = (bf16*) (ws + 0x9080000);   // spp out hi [256][3072]
  bf16*  Slo  = (bf16*) (ws + 0x9200000);
  float* G6   = (float*)(ws + 0x9380000);   // fc1 out fp32 [256][2048]
  bf16*  CChi = (bf16*) (ws + 0x9580000);   // concat hi [256][8192] = 4 MB
  bf16*  CClo = (bf16*) (ws + 0x9980000);
  float* G7   = (float*)(ws + 0x9D80000);   // fc2 out fp32 [256][2048]
  float* PART = (float*)(ws + 0x9F80000);   // 768 KB
  float* SC   = (float*)(ws + 0xA040000);
  float* SH   = (float*)(ws + 0xA050000);

  // ---- weight transforms ----
  wconv_k<64, 128, 5><<<800, 256, 0, stream>>>(c2w, Wc2h, nullptr);
  wconv_k<128, 256, 3><<<1152, 256, 0, stream>>>(c3w, Wc3h, nullptr);
  wconv_k<256, 512, 3><<<4608, 256, 0, stream>>>(c4w, Wc4h, nullptr);
  wconv_k<512, 512, 3><<<9216, 256, 0, stream>>>(c5w, Wc5h, Wc5l);
  cast_k<<<6144, 256, 0, stream>>>(f1w, Wf1, 2048 * 3072 / 4);
  wfc2_k<<<16384, 256, 0, stream>>>(f2w, Wf2);
  phoc_cc_k<<<6144, 256, 0, stream>>>(phoc, CChi, CClo);

  // ---- conv1 (two-pass, no big fp32 buffer) ----
  pad_edge_k<<<1716, 256, 0, stream>>>(x, P);
  conv1_stats_k<<<dim3(96, 8), 256, 0, stream>>>(P, c1w, PART);
  bn_finalize<<<1, 64, 0, stream>>>(PART, g1, b1, SC, SH, 64, 96, 1.f / 393216.f);
  hipMemsetAsync(Ahi, 0, (size_t)64 * 28 * 68 * 64 * 2, stream);
  hipMemsetAsync(Alo, 0, (size_t)64 * 28 * 68 * 64 * 2, stream);
  conv1_apply_k<<<dim3(384, 8), 256, 0, stream>>>(P, c1w, SC, SH, Ahi, Alo);

  // ---- conv2 (1-pass, A-resident): A[98304][1600] -> C[98304][128] ----
  conv2_gemm_k<<<768, 256, 0, stream>>>(Ahi, Wc2h, C, PART);
  bn_finalize<<<1, 128, 0, stream>>>(PART, g2, b2, SC, SH, 128, 768, 1.f / 98304.f);
  bn_act_pad_k<128, 24, 64, true, 1><<<15232, 256, 0, stream>>>(C, SC, SH, Ahi, Alo);

  // ---- conv3 (2-pass: Ah.Bh + Al.Bh) ----
  conv_gemm_k<128, 3, 12, 32, 256, true, false, 1><<<dim3(192, 2), 256, 0, stream>>>(Ahi, Alo, Wc3h, nullptr, C, PART);
  bn_finalize<<<1, 256, 0, stream>>>(PART, g3, b3, SC, SH, 256, 192, 1.f / 24576.f);
  bn_act_pad_k<256, 12, 32, false, 1><<<30464, 256, 0, stream>>>(C, SC, SH, Ahi, Alo);

  // ---- conv4 (1-pass) ----
  conv_gemm_k<256, 3, 12, 32, 512, false, false, 1><<<dim3(192, 4), 256, 0, stream>>>(Ahi, Alo, Wc4h, nullptr, C, PART);
  bn_finalize<<<2, 256, 0, stream>>>(PART, g4, b4, SC, SH, 512, 192, 1.f / 24576.f);
  bn_act_pad_k<512, 12, 32, true, 1><<<18432, 256, 0, stream>>>(C, SC, SH, Ahi, Alo);

  // ---- conv5 (3-pass, split-K=2): partial slabs in C, final in C5F ----
  conv_gemm_k<512, 3, 6, 16, 512, true, true, 2><<<dim3(48, 4, 2), 256, 0, stream>>>(Ahi, Alo, Wc5h, Wc5l, C, nullptr);
  reduce_bn_k<6144, 512, 2, 16><<<dim3(8, 16), 256, 0, stream>>>(C, C5F, PART);
  bn_finalize<<<2, 256, 0, stream>>>(PART, g5, b5, SC, SH, 512, 16, 1.f / 6144.f);
  bn_act_pad_k<512, 6, 16, false, 0><<<12288, 256, 0, stream>>>(C5F, SC, SH, Ahi, Alo);  // feat

  // ---- SPP ----
  spp_k<<<dim3(2, 256), 256, 0, stream>>>(Ahi, Alo, roi, Shi, Slo);

  // ---- FC1 (2-pass, split-K=8): [256][3072] x [2048][3072] ----
  conv_gemm_k<3072, 1, 2, 2, 2048, true, false, 8><<<dim3(2, 16, 8), 256, 0, stream>>>(Shi, Slo, Wf1, nullptr, C, nullptr);
  reduce_bn_k<256, 2048, 8, 4><<<dim3(32, 4), 256, 0, stream>>>(C, G6, PART);
  bn_finalize<<<8, 256, 0, stream>>>(PART, g6, b6, SC, SH, 2048, 4, 1.f / 256.f);
  bn1d_apply_cc_k<<<2048, 256, 0, stream>>>(G6, SC, SH, CChi, CClo);

  // ---- FC2 (2-pass, split-K=8): [256][8192] x [2048][8192] ----
  conv_gemm_k<8192, 1, 2, 2, 2048, true, false, 8><<<dim3(2, 16, 8), 256, 0, stream>>>(CChi, CClo, Wf2, nullptr, C, nullptr);
  reduce_bn_k<256, 2048, 8, 4><<<dim3(32, 4), 256, 0, stream>>>(C, G7, PART);
  bn_finalize<<<8, 256, 0, stream>>>(PART, g7, b7, SC, SH, 2048, 4, 1.f / 256.f);
  bn1d_apply_f32_k<<<2048, 256, 0, stream>>>(G7, SC, SH, out);
}

// Round 12
// 604.208 us; speedup vs baseline: 2.0695x; 1.2206x over previous
//
#include <hip/hip_runtime.h>
#include <hip/hip_bf16.h>

// ============================================================================
// HWNet-SPP forward, MFMA bf16 implicit-GEMM with selective hi/lo precision.
// conv2 uses an A-RESIDENT kernel (receptive field staged once, K-loop only
// streams B). Other layers use the proven 128x128 streaming template.
// Pass config per layer (error budget vs absmax threshold 0.098):
//   conv2: Ah*Bh                (1-pass)   conv3: Ah*Bh + Al*Bh  (2-pass)
//   conv4: Ah*Bh                (1-pass)   conv5: full 3-pass hi/lo
//   FC1/FC2: Ah*Bh + Al*Bh      (2-pass)
// BN column stats fused into GEMM epilogue (SPLIT==1) or split-K reducer;
// bn_finalize is one-block-per-channel with wave butterfly (deterministic).
// Epilogues vectorized 8-ch/thread; conv1 halo fused (no memsets).
// Conv/FC biases skipped (BN mean-subtraction cancels them exactly).
// ============================================================================

typedef __bf16 bf16;
using bf16x4 = __attribute__((ext_vector_type(4))) __bf16;
using bf16x8 = __attribute__((ext_vector_type(8))) __bf16;
using f32x4  = __attribute__((ext_vector_type(4))) float;

__device__ __forceinline__ void split2(float v, bf16& h, bf16& l) {
  bf16 hb = (bf16)v;
  h = hb;
  l = (bf16)(v - (float)hb);
}

__device__ __forceinline__ void gld_lds16(const bf16* g, void* lds) {
  __builtin_amdgcn_global_load_lds(
      (const __attribute__((address_space(1))) unsigned int*)g,
      (__attribute__((address_space(3))) unsigned int*)lds, 16, 0, 0);
}

// ---------------- pad (edge mode, +2 each side of 48x128) ----------------
__global__ __launch_bounds__(256) void pad_edge_k(const float* __restrict__ x,
                                                  float* __restrict__ p) {
  int i = blockIdx.x * 256 + threadIdx.x;
  const int TOT = 64 * 52 * 132;
  if (i >= TOT) return;
  int w = i % 132; int t = i / 132; int h = t % 52; int n = t / 52;
  int sh = h - 2; sh = sh < 0 ? 0 : (sh > 47 ? 47 : sh);
  int sw = w - 2; sw = sw < 0 ? 0 : (sw > 127 ? 127 : sw);
  p[i] = x[(n * 48 + sh) * 128 + sw];
}

// ---------------- conv1 pass 1: BN stats only (fp32, recompute style) ------
__global__ __launch_bounds__(256) void conv1_stats_k(const float* __restrict__ P,
                                                     const float* __restrict__ wt,
                                                     float* __restrict__ part) {
  int co0 = blockIdx.y * 8;
  float sums[8] = {0.f}, sqs[8] = {0.f};
  for (int r = 0; r < 16; r++) {
    int pix = blockIdx.x * 4096 + r * 256 + threadIdx.x;  // 0..393215
    int w = pix & 127; int t = pix >> 7; int h = t % 48; int n = t / 48;
    const float* ip = P + ((size_t)n * 52 + h) * 132 + w;
    float win[25];
#pragma unroll
    for (int kh = 0; kh < 5; kh++)
#pragma unroll
      for (int kw = 0; kw < 5; kw++) win[kh * 5 + kw] = ip[kh * 132 + kw];
#pragma unroll
    for (int j = 0; j < 8; j++) {
      const float* wp = wt + (size_t)(co0 + j) * 25;
      float acc = 0.f;
#pragma unroll
      for (int k = 0; k < 25; k++) acc += win[k] * wp[k];
      sums[j] += acc; sqs[j] += acc * acc;
    }
  }
  __shared__ float ls[256], lq[256];
  for (int j = 0; j < 8; j++) {
    ls[threadIdx.x] = sums[j]; lq[threadIdx.x] = sqs[j];
    __syncthreads();
    for (int o = 128; o > 0; o >>= 1) {
      if (threadIdx.x < o) { ls[threadIdx.x] += ls[threadIdx.x + o]; lq[threadIdx.x] += lq[threadIdx.x + o]; }
      __syncthreads();
    }
    if (threadIdx.x == 0) {
      int c = co0 + j;
      part[((size_t)c * 96 + blockIdx.x) * 2 + 0] = ls[0];
      part[((size_t)c * 96 + blockIdx.x) * 2 + 1] = lq[0];
    }
    __syncthreads();
  }
}

// ---------------- conv1 pass 2: conv+BN+ReLU+pool+pad -> hi/lo -------------
// Covers the PADDED output domain [64][28][68]; halo lanes write zeros.
__global__ __launch_bounds__(256) void conv1_apply_k(const float* __restrict__ P,
                                                     const float* __restrict__ wt,
                                                     const float* __restrict__ scale,
                                                     const float* __restrict__ shift,
                                                     bf16* __restrict__ yh,
                                                     bf16* __restrict__ yl) {
  int i = blockIdx.x * 256 + threadIdx.x;  // 0..121855 padded pixel slots
  if (i >= 64 * 28 * 68) return;
  int owp = i % 68; int t = i / 68; int ohp = t % 28; int n = t / 28;
  int co0 = blockIdx.y * 8;
  int oh = ohp - 2, ow = owp - 2;
  bf16x8 hv, lv;
#pragma unroll
  for (int j = 0; j < 8; j++) { hv[j] = (bf16)0.f; lv[j] = (bf16)0.f; }
  if (oh >= 0 && oh < 24 && ow >= 0 && ow < 64) {
    const float* ip = P + ((size_t)n * 52 + 2 * oh) * 132 + 2 * ow;
    float win[36];
#pragma unroll
    for (int r = 0; r < 6; r++)
#pragma unroll
      for (int c = 0; c < 6; c++) win[r * 6 + c] = ip[r * 132 + c];
#pragma unroll
    for (int j = 0; j < 8; j++) {
      const float* wp = wt + (size_t)(co0 + j) * 25;
      float sc = scale[co0 + j], sh = shift[co0 + j];
      float m = -1e30f;
#pragma unroll
      for (int dy = 0; dy < 2; dy++)
#pragma unroll
        for (int dx = 0; dx < 2; dx++) {
          float acc = 0.f;
#pragma unroll
          for (int kh = 0; kh < 5; kh++)
#pragma unroll
            for (int kw = 0; kw < 5; kw++)
              acc += win[(kh + dy) * 6 + kw + dx] * wp[kh * 5 + kw];
          m = fmaxf(m, acc * sc + sh);
        }
      float v = fmaxf(m, 0.f);
      bf16 h, l; split2(v, h, l);
      hv[j] = h; lv[j] = l;
    }
  }
  size_t o = (size_t)i * 64 + co0;
  *(bf16x8*)(yh + o) = hv;
  *(bf16x8*)(yl + o) = lv;
}

// ---------------- conv2 specialized: A-resident implicit GEMM --------------
__global__ __launch_bounds__(256) void conv2_gemm_k(const bf16* __restrict__ Ahi,
                                                    const bf16* __restrict__ Bhi,
                                                    float* __restrict__ Cout,
                                                    float* __restrict__ part) {
  __shared__ bf16 Ash[416 * 64];      // 52 KB
  __shared__ bf16 Bsh[128 * 64];      // 16 KB
  __shared__ float red[2][128][8];    // 8 KB
  const int t = threadIdx.x;
  const int lane = t & 63, w = t >> 6;
  const int m0 = blockIdx.x * 128;
  const int img = m0 / 1536;
  const int oh0 = (m0 % 1536) >> 6;
  const size_t abase = ((size_t)(img * 28 + oh0) * 68) * 64;

#pragma unroll
  for (int i = 0; i < 13; i++) {
    int f = i * 256 + t;
    int p = f >> 3; if (p > 407) p = 407;
    int s = f & 7;
    int ss = s ^ (p & 7);
    gld_lds16(Ahi + abase + (size_t)p * 64 + ss * 8,
              (char*)Ash + (size_t)(i * 256 + w * 64) * 16);
  }

  size_t boff[4];
#pragma unroll
  for (int i = 0; i < 4; i++) {
    int f = (i * 4 + w) * 64 + lane;
    int row = f >> 3, slot = f & 7;
    int ss = slot ^ (row & 7);
    boff[i] = (size_t)row * 1600 + ss * 8;
  }

  const int wrow = w >> 1, wcol = w & 1;
  const int kg = lane >> 4, l15 = lane & 15;
  int pixb[4];
#pragma unroll
  for (int q = 0; q < 4; q++) pixb[q] = wrow * 68 + q * 16 + l15;
  int brb[4], bmk[4];
#pragma unroll
  for (int q = 0; q < 4; q++) {
    int rb = wcol * 64 + q * 16 + l15;
    brb[q] = rb * 128; bmk[q] = rb & 7;
  }
  const char* Ashb = (const char*)Ash;
  const char* Bshb = (const char*)Bsh;

  f32x4 acc[4][4] = {};
  for (int kc = 0; kc < 25; ++kc) {
    const int kh = kc / 5, kw = kc % 5;
    const int kofs = kh * 68 + kw;
    const int k0 = kc * 64;
#pragma unroll
    for (int i = 0; i < 4; i++)
      gld_lds16(Bhi + boff[i] + k0, (char*)Bsh + (i * 4 + w) * 1024);
    __syncthreads();
#pragma unroll
    for (int ks = 0; ks < 2; ks++) {
      const int slot = ks * 4 + kg;
      bf16x8 ah[4], bh[4];
#pragma unroll
      for (int q = 0; q < 4; q++) {
        int pix = pixb[q] + kofs;
        ah[q] = *(const bf16x8*)(Ashb + pix * 128 + ((slot ^ (pix & 7)) << 4));
        bh[q] = *(const bf16x8*)(Bshb + brb[q] + ((slot ^ bmk[q]) << 4));
      }
#pragma unroll
      for (int mi = 0; mi < 4; mi++)
#pragma unroll
        for (int ni = 0; ni < 4; ni++)
          acc[mi][ni] = __builtin_amdgcn_mfma_f32_16x16x32_bf16(ah[mi], bh[ni], acc[mi][ni], 0, 0, 0);
    }
    __syncthreads();
  }

  const int crow0 = kg * 4, ccol = l15;
#pragma unroll
  for (int mi = 0; mi < 4; mi++) {
    int m = m0 + wrow * 64 + mi * 16 + crow0;
#pragma unroll
    for (int ni = 0; ni < 4; ni++) {
      int nn = wcol * 64 + ni * 16 + ccol;
      float* cp = Cout + (size_t)m * 128 + nn;
#pragma unroll
      for (int jj = 0; jj < 4; jj++) cp[(size_t)jj * 128] = acc[mi][ni][jj];
    }
  }
  const int contrib = kg * 2 + wrow;
#pragma unroll
  for (int ni = 0; ni < 4; ni++) {
    float s = 0.f, q = 0.f;
#pragma unroll
    for (int mi = 0; mi < 4; mi++)
#pragma unroll
      for (int jj = 0; jj < 4; jj++) {
        float v = acc[mi][ni][jj];
        s += v; q += v * v;
      }
    int coll = wcol * 64 + ni * 16 + ccol;
    red[0][coll][contrib] = s;
    red[1][coll][contrib] = q;
  }
  __syncthreads();
  if (t < 128) {
    float s = 0.f, q = 0.f;
#pragma unroll
    for (int j = 0; j < 8; j++) { s += red[0][t][j]; q += red[1][t][j]; }
    size_t c = t;
    part[(c * gridDim.x + blockIdx.x) * 2 + 0] = s;
    part[(c * gridDim.x + blockIdx.x) * 2 + 1] = q;
  }
}

// ---------------- MFMA implicit-GEMM, selective hi/lo, optional split-K ----
template<int CI, int KS, int OH, int OW, int CO, bool ALO, bool BLO, int SPLIT>
__global__ __launch_bounds__(256) void conv_gemm_k(const bf16* __restrict__ Ahi,
                                                   const bf16* __restrict__ Alo,
                                                   const bf16* __restrict__ Bhi,
                                                   const bf16* __restrict__ Blo,
                                                   float* __restrict__ Cout,
                                                   float* __restrict__ part) {
  static_assert(CI % 64 == 0, "chunk must not straddle ci segments");
  constexpr int K = KS * KS * CI;
  constexpr int IWP = OW + KS - 1;
  constexpr int NCH = K / 64;
  static_assert(NCH % SPLIT == 0, "split must divide chunk count");
  constexpr int NCHS = NCH / SPLIT;
  constexpr int M = 64 * OH * OW;
  __shared__ bf16 Ash[128 * 64];
  __shared__ bf16 Asl[ALO ? 128 * 64 : 64];
  __shared__ bf16 Bsh[128 * 64];
  __shared__ bf16 Bsl[BLO ? 128 * 64 : 64];
  __shared__ float red[2][128][8];
  const int t = threadIdx.x;
  const int lane = t & 63, w = t >> 6;
  const int m0 = blockIdx.x * 128, n0 = blockIdx.y * 128;
  const int z = (SPLIT > 1) ? blockIdx.z : 0;

  int apix[4]; size_t boff[4];
#pragma unroll
  for (int i = 0; i < 4; i++) {
    int f = (i * 4 + w) * 64 + lane;
    int row = f >> 3, slot = f & 7;
    int ss = slot ^ (row & 7);
    int m = m0 + row;
    int n = m / (OH * OW); int rem = m % (OH * OW);
    int oh = rem / OW, ow_ = rem % OW;
    apix[i] = ((n * (OH + KS - 1) + oh) * IWP + ow_) * CI + ss * 8;
    boff[i] = (size_t)(n0 + row) * K + ss * 8;
  }

  const int wrow = w >> 1, wcol = w & 1;
  const int kg = lane >> 4, l15 = lane & 15;
  int arb[4], amk[4], brb[4], bmk[4];
#pragma unroll
  for (int q = 0; q < 4; q++) {
    int ra = wrow * 64 + q * 16 + l15;
    arb[q] = ra * 128; amk[q] = ra & 7;
    int rb = wcol * 64 + q * 16 + l15;
    brb[q] = rb * 128; bmk[q] = rb & 7;
  }
  const char* Ashb = (const char*)Ash;
  const char* Aslb = (const char*)Asl;
  const char* Bshb = (const char*)Bsh;
  const char* Bslb = (const char*)Bsl;

  f32x4 acc[4][4] = {};
  for (int kc = z * NCHS; kc < (z + 1) * NCHS; ++kc) {
    const int k0 = kc * 64;
    const int seg = k0 / CI;
    const int ci0 = k0 % CI;
    const int kh = seg / KS, kw = seg % KS;
    const int aoff = (kh * IWP + kw) * CI + ci0;   // wave-uniform
#pragma unroll
    for (int i = 0; i < 4; i++) {
      gld_lds16(Ahi + (size_t)apix[i] + aoff, (char*)Ash + (i * 4 + w) * 1024);
      if (ALO)
        gld_lds16(Alo + (size_t)apix[i] + aoff, (char*)Asl + (i * 4 + w) * 1024);
      gld_lds16(Bhi + boff[i] + k0,   (char*)Bsh + (i * 4 + w) * 1024);
      if (BLO)
        gld_lds16(Blo + boff[i] + k0, (char*)Bsl + (i * 4 + w) * 1024);
    }
    __syncthreads();
#pragma unroll
    for (int ks = 0; ks < 2; ks++) {
      const int slot = ks * 4 + kg;
      bf16x8 ah[4], bh[4];
#pragma unroll
      for (int q = 0; q < 4; q++) {
        ah[q] = *(const bf16x8*)(Ashb + arb[q] + ((slot ^ amk[q]) << 4));
        bh[q] = *(const bf16x8*)(Bshb + brb[q] + ((slot ^ bmk[q]) << 4));
      }
#pragma unroll
      for (int mi = 0; mi < 4; mi++)
#pragma unroll
        for (int ni = 0; ni < 4; ni++)
          acc[mi][ni] = __builtin_amdgcn_mfma_f32_16x16x32_bf16(ah[mi], bh[ni], acc[mi][ni], 0, 0, 0);
      if (ALO) {
        bf16x8 al[4];
#pragma unroll
        for (int q = 0; q < 4; q++)
          al[q] = *(const bf16x8*)(Aslb + arb[q] + ((slot ^ amk[q]) << 4));
#pragma unroll
        for (int mi = 0; mi < 4; mi++)
#pragma unroll
          for (int ni = 0; ni < 4; ni++)
            acc[mi][ni] = __builtin_amdgcn_mfma_f32_16x16x32_bf16(al[mi], bh[ni], acc[mi][ni], 0, 0, 0);
      }
      if (BLO) {
        bf16x8 bl[4];
#pragma unroll
        for (int q = 0; q < 4; q++)
          bl[q] = *(const bf16x8*)(Bslb + brb[q] + ((slot ^ bmk[q]) << 4));
#pragma unroll
        for (int mi = 0; mi < 4; mi++)
#pragma unroll
          for (int ni = 0; ni < 4; ni++)
            acc[mi][ni] = __builtin_amdgcn_mfma_f32_16x16x32_bf16(ah[mi], bl[ni], acc[mi][ni], 0, 0, 0);
      }
    }
    __syncthreads();
  }

  const int crow0 = kg * 4, ccol = l15;
  float* Cz = Cout + (size_t)z * M * CO;
#pragma unroll
  for (int mi = 0; mi < 4; mi++) {
    int m = m0 + wrow * 64 + mi * 16 + crow0;
#pragma unroll
    for (int ni = 0; ni < 4; ni++) {
      int nn = n0 + wcol * 64 + ni * 16 + ccol;
      float* cp = Cz + (size_t)m * CO + nn;
#pragma unroll
      for (int jj = 0; jj < 4; jj++) cp[(size_t)jj * CO] = acc[mi][ni][jj];
    }
  }
  if constexpr (SPLIT == 1) {
    const int contrib = kg * 2 + wrow;
#pragma unroll
    for (int ni = 0; ni < 4; ni++) {
      float s = 0.f, q = 0.f;
#pragma unroll
      for (int mi = 0; mi < 4; mi++)
#pragma unroll
        for (int jj = 0; jj < 4; jj++) {
          float v = acc[mi][ni][jj];
          s += v; q += v * v;
        }
      int coll = wcol * 64 + ni * 16 + ccol;
      red[0][coll][contrib] = s;
      red[1][coll][contrib] = q;
    }
    __syncthreads();
    if (t < 128) {
      float s = 0.f, q = 0.f;
#pragma unroll
      for (int j = 0; j < 8; j++) { s += red[0][t][j]; q += red[1][t][j]; }
      size_t c = n0 + t;
      part[(c * gridDim.x + blockIdx.x) * 2 + 0] = s;
      part[(c * gridDim.x + blockIdx.x) * 2 + 1] = q;
    }
  }
}

// ---------------- split-K reduction + BN partials ----------------
template<int M, int CO, int SPLIT, int NS>
__global__ __launch_bounds__(256) void reduce_bn_k(const float* __restrict__ Cp,
                                                   float* __restrict__ Cf,
                                                   float* __restrict__ part) {
  int c = blockIdx.x * 64 + (threadIdx.x & 63);
  int rl = threadIdx.x >> 6;
  constexpr int ROWS = M / NS;
  int r0 = blockIdx.y * ROWS;
  float sum = 0.f, sq = 0.f;
  for (int r = r0 + rl; r < r0 + ROWS; r += 4) {
    float v = 0.f;
#pragma unroll
    for (int s = 0; s < SPLIT; s++) v += Cp[(size_t)s * M * CO + (size_t)r * CO + c];
    Cf[(size_t)r * CO + c] = v;
    sum += v; sq += v * v;
  }
  __shared__ float ls[256], lq[256];
  ls[threadIdx.x] = sum; lq[threadIdx.x] = sq;
  __syncthreads();
  if (threadIdx.x < 64) {
    sum = ls[threadIdx.x] + ls[threadIdx.x + 64] + ls[threadIdx.x + 128] + ls[threadIdx.x + 192];
    sq  = lq[threadIdx.x] + lq[threadIdx.x + 64] + lq[threadIdx.x + 128] + lq[threadIdx.x + 192];
    part[((size_t)c * NS + blockIdx.y) * 2 + 0] = sum;
    part[((size_t)c * NS + blockIdx.y) * 2 + 1] = sq;
  }
}

// ---------------- BN finalize: one block per channel, wave butterfly -------
__global__ __launch_bounds__(64) void bn_finalize(const float* __restrict__ part,
                                                  const float* __restrict__ g,
                                                  const float* __restrict__ b,
                                                  float* __restrict__ scale,
                                                  float* __restrict__ shift,
                                                  int S, float invCount) {
  int c = blockIdx.x;
  int lane = threadIdx.x;
  float sum = 0.f, sq = 0.f;
  for (int s = lane; s < S; s += 64) {
    sum += part[((size_t)c * S + s) * 2 + 0];
    sq  += part[((size_t)c * S + s) * 2 + 1];
  }
#pragma unroll
  for (int o = 32; o > 0; o >>= 1) {
    sum += __shfl_xor(sum, o);
    sq  += __shfl_xor(sq, o);
  }
  if (lane == 0) {
    float m = sum * invCount;
    float var = sq * invCount - m * m;
    float sc = g[c] * rsqrtf(var + 1e-5f);
    scale[c] = sc;
    shift[c] = b[c] - m * sc;
  }
}

// ---------------- fused BN + ReLU (+2x2 pool) + pad, 8ch/thread ------------
// Index space covers the PADDED output; halo lanes write zeros.
template<int CO, int IH, int IW, bool POOL, int PADO>
__global__ __launch_bounds__(256) void bn_act_pad_k(const float* __restrict__ x,
                                                    const float* __restrict__ scale,
                                                    const float* __restrict__ shift,
                                                    bf16* __restrict__ yh,
                                                    bf16* __restrict__ yl) {
  constexpr int OH2 = POOL ? IH / 2 : IH, OW2 = POOL ? IW / 2 : IW;
  constexpr int OHP = OH2 + 2 * PADO, OWP = OW2 + 2 * PADO;
  constexpr int CO8 = CO / 8;
  int i = blockIdx.x * 256 + threadIdx.x;
  if (i >= 64 * OHP * OWP * CO8) return;
  int c8 = i % CO8; int t = i / CO8; int owp = t % OWP; t /= OWP; int ohp = t % OHP; int n = t / OHP;
  int c0 = c8 * 8;
  int oh = ohp - PADO, ow = owp - PADO;
  bf16x8 hv, lv;
#pragma unroll
  for (int j = 0; j < 8; j++) { hv[j] = (bf16)0.f; lv[j] = (bf16)0.f; }
  if (oh >= 0 && oh < OH2 && ow >= 0 && ow < OW2) {
    float sc[8], sh[8];
    *(f32x4*)(sc)     = *(const f32x4*)(scale + c0);
    *(f32x4*)(sc + 4) = *(const f32x4*)(scale + c0 + 4);
    *(f32x4*)(sh)     = *(const f32x4*)(shift + c0);
    *(f32x4*)(sh + 4) = *(const f32x4*)(shift + c0 + 4);
    float v[8];
    if (POOL) {
      const float* p = x + (((size_t)(n * IH) + oh * 2) * IW + ow * 2) * CO + c0;
      float ta[8], tb[8], tc[8], td[8];
      *(f32x4*)(ta) = *(const f32x4*)(p);            *(f32x4*)(ta + 4) = *(const f32x4*)(p + 4);
      *(f32x4*)(tb) = *(const f32x4*)(p + CO);       *(f32x4*)(tb + 4) = *(const f32x4*)(p + CO + 4);
      *(f32x4*)(tc) = *(const f32x4*)(p + (size_t)IW * CO);
      *(f32x4*)(tc + 4) = *(const f32x4*)(p + (size_t)IW * CO + 4);
      *(f32x4*)(td) = *(const f32x4*)(p + (size_t)(IW + 1) * CO);
      *(f32x4*)(td + 4) = *(const f32x4*)(p + (size_t)(IW + 1) * CO + 4);
#pragma unroll
      for (int j = 0; j < 8; j++) {
        float a = ta[j] * sc[j] + sh[j];
        float b2 = tb[j] * sc[j] + sh[j];
        float d = tc[j] * sc[j] + sh[j];
        float e = td[j] * sc[j] + sh[j];
        v[j] = fmaxf(fmaxf(a, b2), fmaxf(d, e));
      }
    } else {
      const float* p = x + (((size_t)(n * OH2) + oh) * OW2 + ow) * CO + c0;
      float ta[8];
      *(f32x4*)(ta) = *(const f32x4*)(p); *(f32x4*)(ta + 4) = *(const f32x4*)(p + 4);
#pragma unroll
      for (int j = 0; j < 8; j++) v[j] = ta[j] * sc[j] + sh[j];
    }
#pragma unroll
    for (int j = 0; j < 8; j++) {
      float vv = fmaxf(v[j], 0.f);
      bf16 h, l; split2(vv, h, l);
      hv[j] = h; lv[j] = l;
    }
  }
  size_t o = (size_t)i * 8;
  *(bf16x8*)(yh + o) = hv;
  *(bf16x8*)(yl + o) = lv;
}

// ---------------- ROI SPP: feat hi/lo [64][6][16][512] -> S hi/lo ----------
__global__ __launch_bounds__(256) void spp_k(const bf16* __restrict__ fh,
                                             const bf16* __restrict__ fl,
                                             const int* __restrict__ roi,
                                             bf16* __restrict__ oh_,
                                             bf16* __restrict__ ol_) {
  int c = blockIdx.x * 256 + threadIdx.x;  // 0..511
  int r = blockIdx.y;                      // 0..255
  const int* rp = roi + r * 5;
  int im = rp[0];
  int c1 = rp[1] >> 3, r1 = rp[2] >> 3, c2 = rp[3] >> 3, r2 = rp[4] >> 3;
  int w = c2 - c1 + 1;
  int lo[6], hi[6];
  int bi = 0;
#pragma unroll
  for (int l = 1; l <= 3; l++)
    for (int k = 0; k < l; k++) {
      lo[bi] = c1 + (k * w) / l;
      hi[bi] = c1 + ((k + 1) * w + l - 1) / l - 1;
      bi++;
    }
  float mx[6];
#pragma unroll
  for (int b = 0; b < 6; b++) mx[b] = -1e30f;
  const bf16* ph = fh + (size_t)im * 96 * 512 + c;
  const bf16* pl = fl + (size_t)im * 96 * 512 + c;
  for (int row = r1; row <= r2; row++)
    for (int col = c1; col <= c2; col++) {
      size_t off = (size_t)(row * 16 + col) * 512;
      float v = (float)ph[off] + (float)pl[off];
#pragma unroll
      for (int b = 0; b < 6; b++)
        if (col >= lo[b] && col <= hi[b]) mx[b] = fmaxf(mx[b], v);
    }
  int idx[6] = {c, 512 + c * 2, 512 + c * 2 + 1, 1536 + c * 3, 1536 + c * 3 + 1, 1536 + c * 3 + 2};
#pragma unroll
  for (int b = 0; b < 6; b++) {
    bf16 h, l; split2(mx[b], h, l);
    oh_[(size_t)r * 3072 + idx[b]] = h;
    ol_[(size_t)r * 3072 + idx[b]] = l;
  }
}

// FC1: BN+ReLU, write hi/lo into CC[:, 0:2048] (ld 8192), 8 feat/thread
__global__ __launch_bounds__(256) void bn1d_apply_cc_k(const float* __restrict__ x,
                                                       const float* __restrict__ scale,
                                                       const float* __restrict__ shift,
                                                       bf16* __restrict__ ch,
                                                       bf16* __restrict__ cl) {
  int i = blockIdx.x * 256 + threadIdx.x;
  if (i >= 256 * 256) return;
  int f8 = i & 255, r = i >> 8;
  int f0 = f8 * 8;
  float xv[8], sc[8], sh[8];
  *(f32x4*)(xv)     = *(const f32x4*)(x + (size_t)r * 2048 + f0);
  *(f32x4*)(xv + 4) = *(const f32x4*)(x + (size_t)r * 2048 + f0 + 4);
  *(f32x4*)(sc)     = *(const f32x4*)(scale + f0);
  *(f32x4*)(sc + 4) = *(const f32x4*)(scale + f0 + 4);
  *(f32x4*)(sh)     = *(const f32x4*)(shift + f0);
  *(f32x4*)(sh + 4) = *(const f32x4*)(shift + f0 + 4);
  bf16x8 hv, lv;
#pragma unroll
  for (int j = 0; j < 8; j++) {
    float v = fmaxf(xv[j] * sc[j] + sh[j], 0.f);
    bf16 h, l; split2(v, h, l);
    hv[j] = h; lv[j] = l;
  }
  *(bf16x8*)(ch + (size_t)r * 8192 + f0) = hv;
  *(bf16x8*)(cl + (size_t)r * 8192 + f0) = lv;
}

// FC2: BN+ReLU, fp32 out, 4 feat/thread
__global__ __launch_bounds__(256) void bn1d_apply_f32_k(const float* __restrict__ x,
                                                        const float* __restrict__ scale,
                                                        const float* __restrict__ shift,
                                                        float* __restrict__ y) {
  int i = blockIdx.x * 256 + threadIdx.x;
  if (i >= 256 * 512) return;
  int f4 = i & 511, r = i >> 9;
  int f0 = f4 * 4;
  f32x4 xv = *(const f32x4*)(x + (size_t)r * 2048 + f0);
  f32x4 sc = *(const f32x4*)(scale + f0);
  f32x4 sh = *(const f32x4*)(shift + f0);
  f32x4 o;
#pragma unroll
  for (int j = 0; j < 4; j++) o[j] = fmaxf(xv[j] * sc[j] + sh[j], 0.f);
  *(f32x4*)(y + (size_t)r * 2048 + f0) = o;
}

// ---------------- weight transforms ----------------
template<int CI, int CO, int KS>
__global__ __launch_bounds__(256) void wconv_k(const float* __restrict__ w,
                                               bf16* __restrict__ oh_,
                                               bf16* __restrict__ ol_) {
  int i = blockIdx.x * 256 + threadIdx.x;
  if (i >= CO * KS * KS * CI) return;
  int ci = i % CI; int t = i / CI; int kw = t % KS; t /= KS; int kh = t % KS; int co = t / KS;
  float v = w[(((size_t)co * CI + ci) * KS + kh) * KS + kw];
  bf16 h, l; split2(v, h, l);
  oh_[i] = h;
  if (ol_) ol_[i] = l;
}

// fp32 -> bf16 cast, 4 elems/thread (n multiple of 4)
__global__ __launch_bounds__(256) void cast_k(const float* __restrict__ x,
                                              bf16* __restrict__ y, int n4) {
  int i = blockIdx.x * 256 + threadIdx.x;
  if (i >= n4) return;
  const float4 v = *(const float4*)(x + (size_t)i * 4);
  bf16x4 o = { (bf16)v.x, (bf16)v.y, (bf16)v.z, (bf16)v.w };
  *(bf16x4*)(y + (size_t)i * 4) = o;
}

// f2w [2048][7901] fp32 -> [2048][8192] bf16 hi (zero tail), 4 elems/thread
__global__ __launch_bounds__(256) void wfc2_k(const float* __restrict__ x,
                                              bf16* __restrict__ y) {
  int i = blockIdx.x * 256 + threadIdx.x;
  if (i >= 2048 * 2048) return;
  int k = (i & 2047) * 4, n = i >> 11;
  const float* xp = x + (size_t)n * 7901 + k;
  bf16x4 o;
#pragma unroll
  for (int j = 0; j < 4; j++) o[j] = (bf16)((k + j < 7901) ? xp[j] : 0.f);
  *(bf16x4*)(y + (size_t)n * 8192 + k) = o;
}

// phoc [256][5853] fp32 -> CC[:, 2048:8192] hi/lo (zero tail cols)
__global__ __launch_bounds__(256) void phoc_cc_k(const float* __restrict__ phoc,
                                                 bf16* __restrict__ ch,
                                                 bf16* __restrict__ cl) {
  int i = blockIdx.x * 256 + threadIdx.x;
  if (i >= 256 * 6144) return;
  int k = i % 6144, r = i / 6144;
  int col = 2048 + k;
  float v = (col < 7901) ? phoc[(size_t)r * 5853 + (col - 2048)] : 0.f;
  bf16 h, l; split2(v, h, l);
  ch[(size_t)r * 8192 + col] = h;
  cl[(size_t)r * 8192 + col] = l;
}

// ============================================================================
extern "C" void kernel_launch(void* const* d_in, const int* in_sizes, int n_in,
                              void* d_out, int out_size, void* d_ws, size_t ws_size,
                              hipStream_t stream) {
  (void)in_sizes; (void)n_in; (void)out_size; (void)ws_size;

  const float* x    = (const float*)d_in[0];
  const int*   roi  = (const int*)  d_in[1];
  const float* phoc = (const float*)d_in[2];
  const float* c1w  = (const float*)d_in[3];
  const float* g1   = (const float*)d_in[5];
  const float* b1   = (const float*)d_in[6];
  const float* c2w  = (const float*)d_in[7];
  const float* g2   = (const float*)d_in[9];
  const float* b2   = (const float*)d_in[10];
  const float* c3w  = (const float*)d_in[11];
  const float* g3   = (const float*)d_in[13];
  const float* b3   = (const float*)d_in[14];
  const float* c4w  = (const float*)d_in[15];
  const float* g4   = (const float*)d_in[17];
  const float* b4   = (const float*)d_in[18];
  const float* c5w  = (const float*)d_in[19];
  const float* g5   = (const float*)d_in[21];
  const float* b5   = (const float*)d_in[22];
  const float* f1w  = (const float*)d_in[23];
  const float* g6   = (const float*)d_in[25];
  const float* b6   = (const float*)d_in[26];
  const float* f2w  = (const float*)d_in[27];
  const float* g7   = (const float*)d_in[29];
  const float* b7   = (const float*)d_in[30];
  float* out = (float*)d_out;

  // ---- workspace layout (total ~168.4 MB) ----
  char* ws = (char*)d_ws;
  float* P    = (float*)(ws + 0x0000000);   // 1.76 MB
  bf16*  Ahi  = (bf16*) (ws + 0x0200000);   // 16 MB
  bf16*  Alo  = (bf16*) (ws + 0x1200000);   // 16 MB
  float* C    = (float*)(ws + 0x2200000);   // 51 MB region (GEMM out / split slabs)
  float* C5F  = (float*)(ws + 0x4200000);   // conv5 final (32MB into C region)
  bf16*  Wc2h = (bf16*) (ws + 0x5500000);
  bf16*  Wc3h = (bf16*) (ws + 0x5570000);
  bf16*  Wc4h = (bf16*) (ws + 0x5600000);
  bf16*  Wc5h = (bf16*) (ws + 0x5840000);
  bf16*  Wf1  = (bf16*) (ws + 0x5CC0000);
  bf16*  Wf2  = (bf16*) (ws + 0x68C0000);   // [2048][8192] = 32 MB
  bf16*  Wc5l = (bf16*) (ws + 0x8C00000);
  bf16*  Shi  = (bf16*) (ws + 0x9080000);   // spp out hi [256][3072]
  bf16*  Slo  = (bf16*) (ws + 0x9200000);
  float* G6   = (float*)(ws + 0x9380000);   // fc1 out fp32 [256][2048]
  bf16*  CChi = (bf16*) (ws + 0x9580000);   // concat hi [256][8192] = 4 MB
  bf16*  CClo = (bf16*) (ws + 0x9980000);
  float* G7   = (float*)(ws + 0x9D80000);   // fc2 out fp32 [256][2048]
  float* PART = (float*)(ws + 0x9F80000);   // 768 KB
  float* SC   = (float*)(ws + 0xA040000);
  float* SH   = (float*)(ws + 0xA050000);

  // ---- weight transforms ----
  wconv_k<64, 128, 5><<<800, 256, 0, stream>>>(c2w, Wc2h, nullptr);
  wconv_k<128, 256, 3><<<1152, 256, 0, stream>>>(c3w, Wc3h, nullptr);
  wconv_k<256, 512, 3><<<4608, 256, 0, stream>>>(c4w, Wc4h, nullptr);
  wconv_k<512, 512, 3><<<9216, 256, 0, stream>>>(c5w, Wc5h, Wc5l);
  cast_k<<<6144, 256, 0, stream>>>(f1w, Wf1, 2048 * 3072 / 4);
  wfc2_k<<<16384, 256, 0, stream>>>(f2w, Wf2);
  phoc_cc_k<<<6144, 256, 0, stream>>>(phoc, CChi, CClo);

  // ---- conv1 (two-pass, halo fused into apply) ----
  pad_edge_k<<<1716, 256, 0, stream>>>(x, P);
  conv1_stats_k<<<dim3(96, 8), 256, 0, stream>>>(P, c1w, PART);
  bn_finalize<<<64, 64, 0, stream>>>(PART, g1, b1, SC, SH, 96, 1.f / 393216.f);
  conv1_apply_k<<<dim3(476, 8), 256, 0, stream>>>(P, c1w, SC, SH, Ahi, Alo);

  // ---- conv2 (1-pass, A-resident): A[98304][1600] -> C[98304][128] ----
  conv2_gemm_k<<<768, 256, 0, stream>>>(Ahi, Wc2h, C, PART);
  bn_finalize<<<128, 64, 0, stream>>>(PART, g2, b2, SC, SH, 768, 1.f / 98304.f);
  bn_act_pad_k<128, 24, 64, true, 1><<<1904, 256, 0, stream>>>(C, SC, SH, Ahi, Alo);

  // ---- conv3 (2-pass: Ah.Bh + Al.Bh) ----
  conv_gemm_k<128, 3, 12, 32, 256, true, false, 1><<<dim3(192, 2), 256, 0, stream>>>(Ahi, Alo, Wc3h, nullptr, C, PART);
  bn_finalize<<<256, 64, 0, stream>>>(PART, g3, b3, SC, SH, 192, 1.f / 24576.f);
  bn_act_pad_k<256, 12, 32, false, 1><<<3808, 256, 0, stream>>>(C, SC, SH, Ahi, Alo);

  // ---- conv4 (1-pass) ----
  conv_gemm_k<256, 3, 12, 32, 512, false, false, 1><<<dim3(192, 4), 256, 0, stream>>>(Ahi, Alo, Wc4h, nullptr, C, PART);
  bn_finalize<<<512, 64, 0, stream>>>(PART, g4, b4, SC, SH, 192, 1.f / 24576.f);
  bn_act_pad_k<512, 12, 32, true, 1><<<2304, 256, 0, stream>>>(C, SC, SH, Ahi, Alo);

  // ---- conv5 (3-pass, split-K=2): partial slabs in C, final in C5F ----
  conv_gemm_k<512, 3, 6, 16, 512, true, true, 2><<<dim3(48, 4, 2), 256, 0, stream>>>(Ahi, Alo, Wc5h, Wc5l, C, nullptr);
  reduce_bn_k<6144, 512, 2, 16><<<dim3(8, 16), 256, 0, stream>>>(C, C5F, PART);
  bn_finalize<<<512, 64, 0, stream>>>(PART, g5, b5, SC, SH, 16, 1.f / 6144.f);
  bn_act_pad_k<512, 6, 16, false, 0><<<1536, 256, 0, stream>>>(C5F, SC, SH, Ahi, Alo);  // feat

  // ---- SPP ----
  spp_k<<<dim3(2, 256), 256, 0, stream>>>(Ahi, Alo, roi, Shi, Slo);

  // ---- FC1 (2-pass, split-K=8): [256][3072] x [2048][3072] ----
  conv_gemm_k<3072, 1, 2, 2, 2048, true, false, 8><<<dim3(2, 16, 8), 256, 0, stream>>>(Shi, Slo, Wf1, nullptr, C, nullptr);
  reduce_bn_k<256, 2048, 8, 4><<<dim3(32, 4), 256, 0, stream>>>(C, G6, PART);
  bn_finalize<<<2048, 64, 0, stream>>>(PART, g6, b6, SC, SH, 4, 1.f / 256.f);
  bn1d_apply_cc_k<<<256, 256, 0, stream>>>(G6, SC, SH, CChi, CClo);

  // ---- FC2 (2-pass, split-K=8): [256][8192] x [2048][8192] ----
  conv_gemm_k<8192, 1, 2, 2, 2048, true, false, 8><<<dim3(2, 16, 8), 256, 0, stream>>>(CChi, CClo, Wf2, nullptr, C, nullptr);
  reduce_bn_k<256, 2048, 8, 4><<<dim3(32, 4), 256, 0, stream>>>(C, G7, PART);
  bn_finalize<<<2048, 64, 0, stream>>>(PART, g7, b7, SC, SH, 4, 1.f / 256.f);
  bn1d_apply_f32_k<<<512, 256, 0, stream>>>(G7, SC, SH, out);
}

// Round 13
// 590.094 us; speedup vs baseline: 2.1190x; 1.0239x over previous
//
#include <hip/hip_runtime.h>
#include <hip/hip_bf16.h>

// ============================================================================
// HWNet-SPP forward, MFMA bf16 implicit-GEMM with selective hi/lo precision.
// conv2 uses an A-RESIDENT kernel; other layers the proven 128x128 template.
// Pass config (error budget vs absmax threshold 0.098):
//   conv2: Ah*Bh (1-pass)  conv3: +Al*Bh (2-pass)  conv4: 1-pass
//   conv5: full 3-pass hi/lo (split-K=3)  FC1/FC2: 2-pass (split-K=16)
// BN stats fused into GEMM epilogue / split-K reducer; bn_finalize is
// one-block-per-channel wave butterfly. conv1 reads x with clamped (edge)
// indexing (no pad buffer). SPP reads conv5's fp32 output directly with
// inline BN (relu commutes with window-max). All weight transforms fused
// into one prep kernel. Conv/FC biases skipped (BN cancels them exactly).
// ============================================================================

typedef __bf16 bf16;
using bf16x4 = __attribute__((ext_vector_type(4))) __bf16;
using bf16x8 = __attribute__((ext_vector_type(8))) __bf16;
using f32x4  = __attribute__((ext_vector_type(4))) float;

__device__ __forceinline__ void split2(float v, bf16& h, bf16& l) {
  bf16 hb = (bf16)v;
  h = hb;
  l = (bf16)(v - (float)hb);
}

__device__ __forceinline__ int iclamp(int v, int lo, int hi) {
  return v < lo ? lo : (v > hi ? hi : v);
}

__device__ __forceinline__ void gld_lds16(const bf16* g, void* lds) {
  __builtin_amdgcn_global_load_lds(
      (const __attribute__((address_space(1))) unsigned int*)g,
      (__attribute__((address_space(3))) unsigned int*)lds, 16, 0, 0);
}

// ---------------- fused weight/input transforms (one kernel) ----------------
__device__ __forceinline__ void wconv_tx(const float* __restrict__ w,
                                         bf16* __restrict__ oh_,
                                         bf16* __restrict__ ol_,
                                         int CI, int KS, int i, int total) {
  if (i >= total) return;
  int ci = i % CI; int t = i / CI; int kw = t % KS; t /= KS; int kh = t % KS; int co = t / KS;
  float v = w[(((size_t)co * CI + ci) * KS + kh) * KS + kw];
  bf16 h, l; split2(v, h, l);
  oh_[i] = h;
  if (ol_) ol_[i] = l;
}

__global__ __launch_bounds__(256) void prep_k(const float* __restrict__ c2w,
                                              const float* __restrict__ c3w,
                                              const float* __restrict__ c4w,
                                              const float* __restrict__ c5w,
                                              const float* __restrict__ f1w,
                                              const float* __restrict__ f2w,
                                              const float* __restrict__ phoc,
                                              bf16* __restrict__ Wc2h,
                                              bf16* __restrict__ Wc3h,
                                              bf16* __restrict__ Wc4h,
                                              bf16* __restrict__ Wc5h,
                                              bf16* __restrict__ Wc5l,
                                              bf16* __restrict__ Wf1,
                                              bf16* __restrict__ Wf2,
                                              bf16* __restrict__ cch,
                                              bf16* __restrict__ ccl) {
  int b = blockIdx.x;
  int tid = threadIdx.x;
  if (b < 800)  { wconv_tx(c2w, Wc2h, nullptr, 64, 5, b * 256 + tid, 204800); return; }
  b -= 800;
  if (b < 1152) { wconv_tx(c3w, Wc3h, nullptr, 128, 3, b * 256 + tid, 294912); return; }
  b -= 1152;
  if (b < 4608) { wconv_tx(c4w, Wc4h, nullptr, 256, 3, b * 256 + tid, 1179648); return; }
  b -= 4608;
  if (b < 9216) { wconv_tx(c5w, Wc5h, Wc5l, 512, 3, b * 256 + tid, 2359296); return; }
  b -= 9216;
  if (b < 6144) {  // f1w cast, 4 elems/thread
    int i = b * 256 + tid;
    const float4 v = *(const float4*)(f1w + (size_t)i * 4);
    bf16x4 o = { (bf16)v.x, (bf16)v.y, (bf16)v.z, (bf16)v.w };
    *(bf16x4*)(Wf1 + (size_t)i * 4) = o;
    return;
  }
  b -= 6144;
  if (b < 16384) {  // f2w [2048][7901] -> [2048][8192] hi, 4 elems/thread
    int i = b * 256 + tid;
    int k = (i & 2047) * 4, n = i >> 11;
    const float* xp = f2w + (size_t)n * 7901 + k;
    bf16x4 o;
#pragma unroll
    for (int j = 0; j < 4; j++) o[j] = (bf16)((k + j < 7901) ? xp[j] : 0.f);
    *(bf16x4*)(Wf2 + (size_t)n * 8192 + k) = o;
    return;
  }
  b -= 16384;
  {  // phoc -> CC[:, 2048:8192] hi/lo
    int i = b * 256 + tid;
    if (i >= 256 * 6144) return;
    int k = i % 6144, r = i / 6144;
    int col = 2048 + k;
    float v = (col < 7901) ? phoc[(size_t)r * 5853 + (col - 2048)] : 0.f;
    bf16 h, l; split2(v, h, l);
    cch[(size_t)r * 8192 + col] = h;
    ccl[(size_t)r * 8192 + col] = l;
  }
}

// ---------------- conv1 pass 1: BN stats (reads x with edge clamp) ---------
__global__ __launch_bounds__(256) void conv1_stats_k(const float* __restrict__ x,
                                                     const float* __restrict__ wt,
                                                     float* __restrict__ part) {
  int co0 = blockIdx.y * 8;
  float sums[8] = {0.f}, sqs[8] = {0.f};
  for (int r = 0; r < 16; r++) {
    int pix = blockIdx.x * 4096 + r * 256 + threadIdx.x;  // 0..393215
    int w = pix & 127; int t = pix >> 7; int h = t % 48; int n = t / 48;
    const float* ip = x + (size_t)n * 48 * 128;
    int ihs[5], iws[5];
#pragma unroll
    for (int k = 0; k < 5; k++) {
      ihs[k] = iclamp(h + k - 2, 0, 47);
      iws[k] = iclamp(w + k - 2, 0, 127);
    }
    float win[25];
#pragma unroll
    for (int kh = 0; kh < 5; kh++)
#pragma unroll
      for (int kw = 0; kw < 5; kw++) win[kh * 5 + kw] = ip[ihs[kh] * 128 + iws[kw]];
#pragma unroll
    for (int j = 0; j < 8; j++) {
      const float* wp = wt + (size_t)(co0 + j) * 25;
      float acc = 0.f;
#pragma unroll
      for (int k = 0; k < 25; k++) acc += win[k] * wp[k];
      sums[j] += acc; sqs[j] += acc * acc;
    }
  }
  __shared__ float ls[256], lq[256];
  for (int j = 0; j < 8; j++) {
    ls[threadIdx.x] = sums[j]; lq[threadIdx.x] = sqs[j];
    __syncthreads();
    for (int o = 128; o > 0; o >>= 1) {
      if (threadIdx.x < o) { ls[threadIdx.x] += ls[threadIdx.x + o]; lq[threadIdx.x] += lq[threadIdx.x + o]; }
      __syncthreads();
    }
    if (threadIdx.x == 0) {
      int c = co0 + j;
      part[((size_t)c * 96 + blockIdx.x) * 2 + 0] = ls[0];
      part[((size_t)c * 96 + blockIdx.x) * 2 + 1] = lq[0];
    }
    __syncthreads();
  }
}

// ---------------- conv1 pass 2: conv+BN+ReLU+pool+pad -> hi/lo -------------
// Padded output domain [64][28][68]; halo lanes write zeros; reads x clamped.
__global__ __launch_bounds__(256) void conv1_apply_k(const float* __restrict__ x,
                                                     const float* __restrict__ wt,
                                                     const float* __restrict__ scale,
                                                     const float* __restrict__ shift,
                                                     bf16* __restrict__ yh,
                                                     bf16* __restrict__ yl) {
  int i = blockIdx.x * 256 + threadIdx.x;  // 0..121855 padded pixel slots
  if (i >= 64 * 28 * 68) return;
  int owp = i % 68; int t = i / 68; int ohp = t % 28; int n = t / 28;
  int co0 = blockIdx.y * 8;
  int oh = ohp - 2, ow = owp - 2;
  bf16x8 hv, lv;
#pragma unroll
  for (int j = 0; j < 8; j++) { hv[j] = (bf16)0.f; lv[j] = (bf16)0.f; }
  if (oh >= 0 && oh < 24 && ow >= 0 && ow < 64) {
    const float* ip = x + (size_t)n * 48 * 128;
    int shr[6], swc[6];
#pragma unroll
    for (int k = 0; k < 6; k++) {
      shr[k] = iclamp(2 * oh + k - 2, 0, 47);
      swc[k] = iclamp(2 * ow + k - 2, 0, 127);
    }
    float win[36];
#pragma unroll
    for (int r = 0; r < 6; r++)
#pragma unroll
      for (int c = 0; c < 6; c++) win[r * 6 + c] = ip[shr[r] * 128 + swc[c]];
#pragma unroll
    for (int j = 0; j < 8; j++) {
      const float* wp = wt + (size_t)(co0 + j) * 25;
      float sc = scale[co0 + j], sh = shift[co0 + j];
      float m = -1e30f;
#pragma unroll
      for (int dy = 0; dy < 2; dy++)
#pragma unroll
        for (int dx = 0; dx < 2; dx++) {
          float acc = 0.f;
#pragma unroll
          for (int kh = 0; kh < 5; kh++)
#pragma unroll
            for (int kw = 0; kw < 5; kw++)
              acc += win[(kh + dy) * 6 + kw + dx] * wp[kh * 5 + kw];
          m = fmaxf(m, acc * sc + sh);
        }
      float v = fmaxf(m, 0.f);
      bf16 h, l; split2(v, h, l);
      hv[j] = h; lv[j] = l;
    }
  }
  size_t o = (size_t)i * 64 + co0;
  *(bf16x8*)(yh + o) = hv;
  *(bf16x8*)(yl + o) = lv;
}

// ---------------- conv2 specialized: A-resident implicit GEMM --------------
__global__ __launch_bounds__(256) void conv2_gemm_k(const bf16* __restrict__ Ahi,
                                                    const bf16* __restrict__ Bhi,
                                                    float* __restrict__ Cout,
                                                    float* __restrict__ part) {
  __shared__ bf16 Ash[416 * 64];      // 52 KB
  __shared__ bf16 Bsh[128 * 64];      // 16 KB
  __shared__ float red[2][128][8];    // 8 KB
  const int t = threadIdx.x;
  const int lane = t & 63, w = t >> 6;
  const int m0 = blockIdx.x * 128;
  const int img = m0 / 1536;
  const int oh0 = (m0 % 1536) >> 6;
  const size_t abase = ((size_t)(img * 28 + oh0) * 68) * 64;

#pragma unroll
  for (int i = 0; i < 13; i++) {
    int f = i * 256 + t;
    int p = f >> 3; if (p > 407) p = 407;
    int s = f & 7;
    int ss = s ^ (p & 7);
    gld_lds16(Ahi + abase + (size_t)p * 64 + ss * 8,
              (char*)Ash + (size_t)(i * 256 + w * 64) * 16);
  }

  size_t boff[4];
#pragma unroll
  for (int i = 0; i < 4; i++) {
    int f = (i * 4 + w) * 64 + lane;
    int row = f >> 3, slot = f & 7;
    int ss = slot ^ (row & 7);
    boff[i] = (size_t)row * 1600 + ss * 8;
  }

  const int wrow = w >> 1, wcol = w & 1;
  const int kg = lane >> 4, l15 = lane & 15;
  int pixb[4];
#pragma unroll
  for (int q = 0; q < 4; q++) pixb[q] = wrow * 68 + q * 16 + l15;
  int brb[4], bmk[4];
#pragma unroll
  for (int q = 0; q < 4; q++) {
    int rb = wcol * 64 + q * 16 + l15;
    brb[q] = rb * 128; bmk[q] = rb & 7;
  }
  const char* Ashb = (const char*)Ash;
  const char* Bshb = (const char*)Bsh;

  f32x4 acc[4][4] = {};
  for (int kc = 0; kc < 25; ++kc) {
    const int kh = kc / 5, kw = kc % 5;
    const int kofs = kh * 68 + kw;
    const int k0 = kc * 64;
#pragma unroll
    for (int i = 0; i < 4; i++)
      gld_lds16(Bhi + boff[i] + k0, (char*)Bsh + (i * 4 + w) * 1024);
    __syncthreads();
#pragma unroll
    for (int ks = 0; ks < 2; ks++) {
      const int slot = ks * 4 + kg;
      bf16x8 ah[4], bh[4];
#pragma unroll
      for (int q = 0; q < 4; q++) {
        int pix = pixb[q] + kofs;
        ah[q] = *(const bf16x8*)(Ashb + pix * 128 + ((slot ^ (pix & 7)) << 4));
        bh[q] = *(const bf16x8*)(Bshb + brb[q] + ((slot ^ bmk[q]) << 4));
      }
#pragma unroll
      for (int mi = 0; mi < 4; mi++)
#pragma unroll
        for (int ni = 0; ni < 4; ni++)
          acc[mi][ni] = __builtin_amdgcn_mfma_f32_16x16x32_bf16(ah[mi], bh[ni], acc[mi][ni], 0, 0, 0);
    }
    __syncthreads();
  }

  const int crow0 = kg * 4, ccol = l15;
#pragma unroll
  for (int mi = 0; mi < 4; mi++) {
    int m = m0 + wrow * 64 + mi * 16 + crow0;
#pragma unroll
    for (int ni = 0; ni < 4; ni++) {
      int nn = wcol * 64 + ni * 16 + ccol;
      float* cp = Cout + (size_t)m * 128 + nn;
#pragma unroll
      for (int jj = 0; jj < 4; jj++) cp[(size_t)jj * 128] = acc[mi][ni][jj];
    }
  }
  const int contrib = kg * 2 + wrow;
#pragma unroll
  for (int ni = 0; ni < 4; ni++) {
    float s = 0.f, q = 0.f;
#pragma unroll
    for (int mi = 0; mi < 4; mi++)
#pragma unroll
      for (int jj = 0; jj < 4; jj++) {
        float v = acc[mi][ni][jj];
        s += v; q += v * v;
      }
    int coll = wcol * 64 + ni * 16 + ccol;
    red[0][coll][contrib] = s;
    red[1][coll][contrib] = q;
  }
  __syncthreads();
  if (t < 128) {
    float s = 0.f, q = 0.f;
#pragma unroll
    for (int j = 0; j < 8; j++) { s += red[0][t][j]; q += red[1][t][j]; }
    size_t c = t;
    part[(c * gridDim.x + blockIdx.x) * 2 + 0] = s;
    part[(c * gridDim.x + blockIdx.x) * 2 + 1] = q;
  }
}

// ---------------- MFMA implicit-GEMM, selective hi/lo, optional split-K ----
template<int CI, int KS, int OH, int OW, int CO, bool ALO, bool BLO, int SPLIT>
__global__ __launch_bounds__(256) void conv_gemm_k(const bf16* __restrict__ Ahi,
                                                   const bf16* __restrict__ Alo,
                                                   const bf16* __restrict__ Bhi,
                                                   const bf16* __restrict__ Blo,
                                                   float* __restrict__ Cout,
                                                   float* __restrict__ part) {
  static_assert(CI % 64 == 0, "chunk must not straddle ci segments");
  constexpr int K = KS * KS * CI;
  constexpr int IWP = OW + KS - 1;
  constexpr int NCH = K / 64;
  static_assert(NCH % SPLIT == 0, "split must divide chunk count");
  constexpr int NCHS = NCH / SPLIT;
  constexpr int M = 64 * OH * OW;
  __shared__ bf16 Ash[128 * 64];
  __shared__ bf16 Asl[ALO ? 128 * 64 : 64];
  __shared__ bf16 Bsh[128 * 64];
  __shared__ bf16 Bsl[BLO ? 128 * 64 : 64];
  __shared__ float red[2][128][8];
  const int t = threadIdx.x;
  const int lane = t & 63, w = t >> 6;
  const int m0 = blockIdx.x * 128, n0 = blockIdx.y * 128;
  const int z = (SPLIT > 1) ? blockIdx.z : 0;

  int apix[4]; size_t boff[4];
#pragma unroll
  for (int i = 0; i < 4; i++) {
    int f = (i * 4 + w) * 64 + lane;
    int row = f >> 3, slot = f & 7;
    int ss = slot ^ (row & 7);
    int m = m0 + row;
    int n = m / (OH * OW); int rem = m % (OH * OW);
    int oh = rem / OW, ow_ = rem % OW;
    apix[i] = ((n * (OH + KS - 1) + oh) * IWP + ow_) * CI + ss * 8;
    boff[i] = (size_t)(n0 + row) * K + ss * 8;
  }

  const int wrow = w >> 1, wcol = w & 1;
  const int kg = lane >> 4, l15 = lane & 15;
  int arb[4], amk[4], brb[4], bmk[4];
#pragma unroll
  for (int q = 0; q < 4; q++) {
    int ra = wrow * 64 + q * 16 + l15;
    arb[q] = ra * 128; amk[q] = ra & 7;
    int rb = wcol * 64 + q * 16 + l15;
    brb[q] = rb * 128; bmk[q] = rb & 7;
  }
  const char* Ashb = (const char*)Ash;
  const char* Aslb = (const char*)Asl;
  const char* Bshb = (const char*)Bsh;
  const char* Bslb = (const char*)Bsl;

  f32x4 acc[4][4] = {};
  for (int kc = z * NCHS; kc < (z + 1) * NCHS; ++kc) {
    const int k0 = kc * 64;
    const int seg = k0 / CI;
    const int ci0 = k0 % CI;
    const int kh = seg / KS, kw = seg % KS;
    const int aoff = (kh * IWP + kw) * CI + ci0;   // wave-uniform
#pragma unroll
    for (int i = 0; i < 4; i++) {
      gld_lds16(Ahi + (size_t)apix[i] + aoff, (char*)Ash + (i * 4 + w) * 1024);
      if (ALO)
        gld_lds16(Alo + (size_t)apix[i] + aoff, (char*)Asl + (i * 4 + w) * 1024);
      gld_lds16(Bhi + boff[i] + k0,   (char*)Bsh + (i * 4 + w) * 1024);
      if (BLO)
        gld_lds16(Blo + boff[i] + k0, (char*)Bsl + (i * 4 + w) * 1024);
    }
    __syncthreads();
#pragma unroll
    for (int ks = 0; ks < 2; ks++) {
      const int slot = ks * 4 + kg;
      bf16x8 ah[4], bh[4];
#pragma unroll
      for (int q = 0; q < 4; q++) {
        ah[q] = *(const bf16x8*)(Ashb + arb[q] + ((slot ^ amk[q]) << 4));
        bh[q] = *(const bf16x8*)(Bshb + brb[q] + ((slot ^ bmk[q]) << 4));
      }
#pragma unroll
      for (int mi = 0; mi < 4; mi++)
#pragma unroll
        for (int ni = 0; ni < 4; ni++)
          acc[mi][ni] = __builtin_amdgcn_mfma_f32_16x16x32_bf16(ah[mi], bh[ni], acc[mi][ni], 0, 0, 0);
      if (ALO) {
        bf16x8 al[4];
#pragma unroll
        for (int q = 0; q < 4; q++)
          al[q] = *(const bf16x8*)(Aslb + arb[q] + ((slot ^ amk[q]) << 4));
#pragma unroll
        for (int mi = 0; mi < 4; mi++)
#pragma unroll
          for (int ni = 0; ni < 4; ni++)
            acc[mi][ni] = __builtin_amdgcn_mfma_f32_16x16x32_bf16(al[mi], bh[ni], acc[mi][ni], 0, 0, 0);
      }
      if (BLO) {
        bf16x8 bl[4];
#pragma unroll
        for (int q = 0; q < 4; q++)
          bl[q] = *(const bf16x8*)(Bslb + brb[q] + ((slot ^ bmk[q]) << 4));
#pragma unroll
        for (int mi = 0; mi < 4; mi++)
#pragma unroll
          for (int ni = 0; ni < 4; ni++)
            acc[mi][ni] = __builtin_amdgcn_mfma_f32_16x16x32_bf16(ah[mi], bl[ni], acc[mi][ni], 0, 0, 0);
      }
    }
    __syncthreads();
  }

  const int crow0 = kg * 4, ccol = l15;
  float* Cz = Cout + (size_t)z * M * CO;
#pragma unroll
  for (int mi = 0; mi < 4; mi++) {
    int m = m0 + wrow * 64 + mi * 16 + crow0;
#pragma unroll
    for (int ni = 0; ni < 4; ni++) {
      int nn = n0 + wcol * 64 + ni * 16 + ccol;
      float* cp = Cz + (size_t)m * CO + nn;
#pragma unroll
      for (int jj = 0; jj < 4; jj++) cp[(size_t)jj * CO] = acc[mi][ni][jj];
    }
  }
  if constexpr (SPLIT == 1) {
    const int contrib = kg * 2 + wrow;
#pragma unroll
    for (int ni = 0; ni < 4; ni++) {
      float s = 0.f, q = 0.f;
#pragma unroll
      for (int mi = 0; mi < 4; mi++)
#pragma unroll
        for (int jj = 0; jj < 4; jj++) {
          float v = acc[mi][ni][jj];
          s += v; q += v * v;
        }
      int coll = wcol * 64 + ni * 16 + ccol;
      red[0][coll][contrib] = s;
      red[1][coll][contrib] = q;
    }
    __syncthreads();
    if (t < 128) {
      float s = 0.f, q = 0.f;
#pragma unroll
      for (int j = 0; j < 8; j++) { s += red[0][t][j]; q += red[1][t][j]; }
      size_t c = n0 + t;
      part[(c * gridDim.x + blockIdx.x) * 2 + 0] = s;
      part[(c * gridDim.x + blockIdx.x) * 2 + 1] = q;
    }
  }
}

// ---------------- split-K reduction + BN partials ----------------
template<int M, int CO, int SPLIT, int NS>
__global__ __launch_bounds__(256) void reduce_bn_k(const float* __restrict__ Cp,
                                                   float* __restrict__ Cf,
                                                   float* __restrict__ part) {
  int c = blockIdx.x * 64 + (threadIdx.x & 63);
  int rl = threadIdx.x >> 6;
  constexpr int ROWS = M / NS;
  int r0 = blockIdx.y * ROWS;
  float sum = 0.f, sq = 0.f;
  for (int r = r0 + rl; r < r0 + ROWS; r += 4) {
    float v = 0.f;
#pragma unroll
    for (int s = 0; s < SPLIT; s++) v += Cp[(size_t)s * M * CO + (size_t)r * CO + c];
    Cf[(size_t)r * CO + c] = v;
    sum += v; sq += v * v;
  }
  __shared__ float ls[256], lq[256];
  ls[threadIdx.x] = sum; lq[threadIdx.x] = sq;
  __syncthreads();
  if (threadIdx.x < 64) {
    sum = ls[threadIdx.x] + ls[threadIdx.x + 64] + ls[threadIdx.x + 128] + ls[threadIdx.x + 192];
    sq  = lq[threadIdx.x] + lq[threadIdx.x + 64] + lq[threadIdx.x + 128] + lq[threadIdx.x + 192];
    part[((size_t)c * NS + blockIdx.y) * 2 + 0] = sum;
    part[((size_t)c * NS + blockIdx.y) * 2 + 1] = sq;
  }
}

// ---------------- BN finalize: one block per channel, wave butterfly -------
__global__ __launch_bounds__(64) void bn_finalize(const float* __restrict__ part,
                                                  const float* __restrict__ g,
                                                  const float* __restrict__ b,
                                                  float* __restrict__ scale,
                                                  float* __restrict__ shift,
                                                  int S, float invCount) {
  int c = blockIdx.x;
  int lane = threadIdx.x;
  float sum = 0.f, sq = 0.f;
  for (int s = lane; s < S; s += 64) {
    sum += part[((size_t)c * S + s) * 2 + 0];
    sq  += part[((size_t)c * S + s) * 2 + 1];
  }
#pragma unroll
  for (int o = 32; o > 0; o >>= 1) {
    sum += __shfl_xor(sum, o);
    sq  += __shfl_xor(sq, o);
  }
  if (lane == 0) {
    float m = sum * invCount;
    float var = sq * invCount - m * m;
    float sc = g[c] * rsqrtf(var + 1e-5f);
    scale[c] = sc;
    shift[c] = b[c] - m * sc;
  }
}

// ---------------- fused BN + ReLU (+2x2 pool) + pad, 8ch/thread ------------
template<int CO, int IH, int IW, bool POOL, int PADO>
__global__ __launch_bounds__(256) void bn_act_pad_k(const float* __restrict__ x,
                                                    const float* __restrict__ scale,
                                                    const float* __restrict__ shift,
                                                    bf16* __restrict__ yh,
                                                    bf16* __restrict__ yl) {
  constexpr int OH2 = POOL ? IH / 2 : IH, OW2 = POOL ? IW / 2 : IW;
  constexpr int OHP = OH2 + 2 * PADO, OWP = OW2 + 2 * PADO;
  constexpr int CO8 = CO / 8;
  int i = blockIdx.x * 256 + threadIdx.x;
  if (i >= 64 * OHP * OWP * CO8) return;
  int c8 = i % CO8; int t = i / CO8; int owp = t % OWP; t /= OWP; int ohp = t % OHP; int n = t / OHP;
  int c0 = c8 * 8;
  int oh = ohp - PADO, ow = owp - PADO;
  bf16x8 hv, lv;
#pragma unroll
  for (int j = 0; j < 8; j++) { hv[j] = (bf16)0.f; lv[j] = (bf16)0.f; }
  if (oh >= 0 && oh < OH2 && ow >= 0 && ow < OW2) {
    float sc[8], sh[8];
    *(f32x4*)(sc)     = *(const f32x4*)(scale + c0);
    *(f32x4*)(sc + 4) = *(const f32x4*)(scale + c0 + 4);
    *(f32x4*)(sh)     = *(const f32x4*)(shift + c0);
    *(f32x4*)(sh + 4) = *(const f32x4*)(shift + c0 + 4);
    float v[8];
    if (POOL) {
      const float* p = x + (((size_t)(n * IH) + oh * 2) * IW + ow * 2) * CO + c0;
      float ta[8], tb[8], tc[8], td[8];
      *(f32x4*)(ta) = *(const f32x4*)(p);            *(f32x4*)(ta + 4) = *(const f32x4*)(p + 4);
      *(f32x4*)(tb) = *(const f32x4*)(p + CO);       *(f32x4*)(tb + 4) = *(const f32x4*)(p + CO + 4);
      *(f32x4*)(tc) = *(const f32x4*)(p + (size_t)IW * CO);
      *(f32x4*)(tc + 4) = *(const f32x4*)(p + (size_t)IW * CO + 4);
      *(f32x4*)(td) = *(const f32x4*)(p + (size_t)(IW + 1) * CO);
      *(f32x4*)(td + 4) = *(const f32x4*)(p + (size_t)(IW + 1) * CO + 4);
#pragma unroll
      for (int j = 0; j < 8; j++) {
        float a = ta[j] * sc[j] + sh[j];
        float b2 = tb[j] * sc[j] + sh[j];
        float d = tc[j] * sc[j] + sh[j];
        float e = td[j] * sc[j] + sh[j];
        v[j] = fmaxf(fmaxf(a, b2), fmaxf(d, e));
      }
    } else {
      const float* p = x + (((size_t)(n * OH2) + oh) * OW2 + ow) * CO + c0;
      float ta[8];
      *(f32x4*)(ta) = *(const f32x4*)(p); *(f32x4*)(ta + 4) = *(const f32x4*)(p + 4);
#pragma unroll
      for (int j = 0; j < 8; j++) v[j] = ta[j] * sc[j] + sh[j];
    }
#pragma unroll
    for (int j = 0; j < 8; j++) {
      float vv = fmaxf(v[j], 0.f);
      bf16 h, l; split2(vv, h, l);
      hv[j] = h; lv[j] = l;
    }
  }
  size_t o = (size_t)i * 8;
  *(bf16x8*)(yh + o) = hv;
  *(bf16x8*)(yl + o) = lv;
}

// ---------------- ROI SPP: reads conv5 fp32 out + inline BN ----------------
// feat[m][c] with m = im*96 + row*16 + col; v = feat*scale[c]+shift[c];
// relu applied after window-max (commutes).
__global__ __launch_bounds__(256) void spp_k(const float* __restrict__ feat,
                                             const float* __restrict__ scale,
                                             const float* __restrict__ shift,
                                             const int* __restrict__ roi,
                                             bf16* __restrict__ oh_,
                                             bf16* __restrict__ ol_) {
  int c = blockIdx.x * 256 + threadIdx.x;  // 0..511
  int r = blockIdx.y;                      // 0..255
  const int* rp = roi + r * 5;
  int im = rp[0];
  int c1 = rp[1] >> 3, r1 = rp[2] >> 3, c2 = rp[3] >> 3, r2 = rp[4] >> 3;
  int w = c2 - c1 + 1;
  int lo[6], hi[6];
  int bi = 0;
#pragma unroll
  for (int l = 1; l <= 3; l++)
    for (int k = 0; k < l; k++) {
      lo[bi] = c1 + (k * w) / l;
      hi[bi] = c1 + ((k + 1) * w + l - 1) / l - 1;
      bi++;
    }
  float mx[6];
#pragma unroll
  for (int b = 0; b < 6; b++) mx[b] = -1e30f;
  float sc = scale[c], sh = shift[c];
  const float* fp = feat + (size_t)im * 96 * 512 + c;
  for (int row = r1; row <= r2; row++)
    for (int col = c1; col <= c2; col++) {
      float v = fp[(size_t)(row * 16 + col) * 512] * sc + sh;
#pragma unroll
      for (int b = 0; b < 6; b++)
        if (col >= lo[b] && col <= hi[b]) mx[b] = fmaxf(mx[b], v);
    }
  int idx[6] = {c, 512 + c * 2, 512 + c * 2 + 1, 1536 + c * 3, 1536 + c * 3 + 1, 1536 + c * 3 + 2};
#pragma unroll
  for (int b = 0; b < 6; b++) {
    float v = fmaxf(mx[b], 0.f);
    bf16 h, l; split2(v, h, l);
    oh_[(size_t)r * 3072 + idx[b]] = h;
    ol_[(size_t)r * 3072 + idx[b]] = l;
  }
}

// FC1: BN+ReLU, write hi/lo into CC[:, 0:2048] (ld 8192), 8 feat/thread
__global__ __launch_bounds__(256) void bn1d_apply_cc_k(const float* __restrict__ x,
                                                       const float* __restrict__ scale,
                                                       const float* __restrict__ shift,
                                                       bf16* __restrict__ ch,
                                                       bf16* __restrict__ cl) {
  int i = blockIdx.x * 256 + threadIdx.x;
  if (i >= 256 * 256) return;
  int f8 = i & 255, r = i >> 8;
  int f0 = f8 * 8;
  float xv[8], sc[8], sh[8];
  *(f32x4*)(xv)     = *(const f32x4*)(x + (size_t)r * 2048 + f0);
  *(f32x4*)(xv + 4) = *(const f32x4*)(x + (size_t)r * 2048 + f0 + 4);
  *(f32x4*)(sc)     = *(const f32x4*)(scale + f0);
  *(f32x4*)(sc + 4) = *(const f32x4*)(scale + f0 + 4);
  *(f32x4*)(sh)     = *(const f32x4*)(shift + f0);
  *(f32x4*)(sh + 4) = *(const f32x4*)(shift + f0 + 4);
  bf16x8 hv, lv;
#pragma unroll
  for (int j = 0; j < 8; j++) {
    float v = fmaxf(xv[j] * sc[j] + sh[j], 0.f);
    bf16 h, l; split2(v, h, l);
    hv[j] = h; lv[j] = l;
  }
  *(bf16x8*)(ch + (size_t)r * 8192 + f0) = hv;
  *(bf16x8*)(cl + (size_t)r * 8192 + f0) = lv;
}

// FC2: BN+ReLU, fp32 out, 4 feat/thread
__global__ __launch_bounds__(256) void bn1d_apply_f32_k(const float* __restrict__ x,
                                                        const float* __restrict__ scale,
                                                        const float* __restrict__ shift,
                                                        float* __restrict__ y) {
  int i = blockIdx.x * 256 + threadIdx.x;
  if (i >= 256 * 512) return;
  int f4 = i & 511, r = i >> 9;
  int f0 = f4 * 4;
  f32x4 xv = *(const f32x4*)(x + (size_t)r * 2048 + f0);
  f32x4 sc = *(const f32x4*)(scale + f0);
  f32x4 sh = *(const f32x4*)(shift + f0);
  f32x4 o;
#pragma unroll
  for (int j = 0; j < 4; j++) o[j] = fmaxf(xv[j] * sc[j] + sh[j], 0.f);
  *(f32x4*)(y + (size_t)r * 2048 + f0) = o;
}

// ============================================================================
extern "C" void kernel_launch(void* const* d_in, const int* in_sizes, int n_in,
                              void* d_out, int out_size, void* d_ws, size_t ws_size,
                              hipStream_t stream) {
  (void)in_sizes; (void)n_in; (void)out_size; (void)ws_size;

  const float* x    = (const float*)d_in[0];
  const int*   roi  = (const int*)  d_in[1];
  const float* phoc = (const float*)d_in[2];
  const float* c1w  = (const float*)d_in[3];
  const float* g1   = (const float*)d_in[5];
  const float* b1   = (const float*)d_in[6];
  const float* c2w  = (const float*)d_in[7];
  const float* g2   = (const float*)d_in[9];
  const float* b2   = (const float*)d_in[10];
  const float* c3w  = (const float*)d_in[11];
  const float* g3   = (const float*)d_in[13];
  const float* b3   = (const float*)d_in[14];
  const float* c4w  = (const float*)d_in[15];
  const float* g4   = (const float*)d_in[17];
  const float* b4   = (const float*)d_in[18];
  const float* c5w  = (const float*)d_in[19];
  const float* g5   = (const float*)d_in[21];
  const float* b5   = (const float*)d_in[22];
  const float* f1w  = (const float*)d_in[23];
  const float* g6   = (const float*)d_in[25];
  const float* b6   = (const float*)d_in[26];
  const float* f2w  = (const float*)d_in[27];
  const float* g7   = (const float*)d_in[29];
  const float* b7   = (const float*)d_in[30];
  float* out = (float*)d_out;

  // ---- workspace layout (total ~168.4 MB) ----
  char* ws = (char*)d_ws;
  bf16*  Ahi  = (bf16*) (ws + 0x0200000);   // 16 MB
  bf16*  Alo  = (bf16*) (ws + 0x1200000);   // 16 MB
  float* C    = (float*)(ws + 0x2200000);   // 53 MB region (GEMM out / split slabs)
  float* C5F  = (float*)(ws + 0x4600000);   // conv5 final (after 3 slabs of 12.6MB)
  bf16*  Wc2h = (bf16*) (ws + 0x5500000);
  bf16*  Wc3h = (bf16*) (ws + 0x5570000);
  bf16*  Wc4h = (bf16*) (ws + 0x5600000);
  bf16*  Wc5h = (bf16*) (ws + 0x5840000);
  bf16*  Wf1  = (bf16*) (ws + 0x5CC0000);
  bf16*  Wf2  = (bf16*) (ws + 0x68C0000);   // [2048][8192] = 32 MB
  bf16*  Wc5l = (bf16*) (ws + 0x8C00000);
  bf16*  Shi  = (bf16*) (ws + 0x9080000);   // spp out hi [256][3072]
  bf16*  Slo  = (bf16*) (ws + 0x9200000);
  float* G6   = (float*)(ws + 0x9380000);   // fc1 out fp32 [256][2048]
  bf16*  CChi = (bf16*) (ws + 0x9580000);   // concat hi [256][8192] = 4 MB
  bf16*  CClo = (bf16*) (ws + 0x9980000);
  float* G7   = (float*)(ws + 0x9D80000);   // fc2 out fp32 [256][2048]
  float* PART = (float*)(ws + 0x9F80000);   // 768 KB
  float* SC   = (float*)(ws + 0xA040000);
  float* SH   = (float*)(ws + 0xA050000);

  // ---- all weight/input transforms in one dispatch ----
  prep_k<<<44448, 256, 0, stream>>>(c2w, c3w, c4w, c5w, f1w, f2w, phoc,
                                    Wc2h, Wc3h, Wc4h, Wc5h, Wc5l, Wf1, Wf2,
                                    CChi, CClo);

  // ---- conv1 (two-pass, clamped reads, halo fused) ----
  conv1_stats_k<<<dim3(96, 8), 256, 0, stream>>>(x, c1w, PART);
  bn_finalize<<<64, 64, 0, stream>>>(PART, g1, b1, SC, SH, 96, 1.f / 393216.f);
  conv1_apply_k<<<dim3(476, 8), 256, 0, stream>>>(x, c1w, SC, SH, Ahi, Alo);

  // ---- conv2 (1-pass, A-resident): A[98304][1600] -> C[98304][128] ----
  conv2_gemm_k<<<768, 256, 0, stream>>>(Ahi, Wc2h, C, PART);
  bn_finalize<<<128, 64, 0, stream>>>(PART, g2, b2, SC, SH, 768, 1.f / 98304.f);
  bn_act_pad_k<128, 24, 64, true, 1><<<1904, 256, 0, stream>>>(C, SC, SH, Ahi, Alo);

  // ---- conv3 (2-pass: Ah.Bh + Al.Bh) ----
  conv_gemm_k<128, 3, 12, 32, 256, true, false, 1><<<dim3(192, 2), 256, 0, stream>>>(Ahi, Alo, Wc3h, nullptr, C, PART);
  bn_finalize<<<256, 64, 0, stream>>>(PART, g3, b3, SC, SH, 192, 1.f / 24576.f);
  bn_act_pad_k<256, 12, 32, false, 1><<<3808, 256, 0, stream>>>(C, SC, SH, Ahi, Alo);

  // ---- conv4 (1-pass) ----
  conv_gemm_k<256, 3, 12, 32, 512, false, false, 1><<<dim3(192, 4), 256, 0, stream>>>(Ahi, Alo, Wc4h, nullptr, C, PART);
  bn_finalize<<<512, 64, 0, stream>>>(PART, g4, b4, SC, SH, 192, 1.f / 24576.f);
  bn_act_pad_k<512, 12, 32, true, 1><<<2304, 256, 0, stream>>>(C, SC, SH, Ahi, Alo);

  // ---- conv5 (3-pass, split-K=3): slabs in C, final in C5F ----
  conv_gemm_k<512, 3, 6, 16, 512, true, true, 3><<<dim3(48, 4, 3), 256, 0, stream>>>(Ahi, Alo, Wc5h, Wc5l, C, nullptr);
  reduce_bn_k<6144, 512, 3, 16><<<dim3(8, 16), 256, 0, stream>>>(C, C5F, PART);
  bn_finalize<<<512, 64, 0, stream>>>(PART, g5, b5, SC, SH, 16, 1.f / 6144.f);

  // ---- SPP (reads fp32 conv5 out + inline BN) ----
  spp_k<<<dim3(2, 256), 256, 0, stream>>>(C5F, SC, SH, roi, Shi, Slo);

  // ---- FC1 (2-pass, split-K=16): [256][3072] x [2048][3072] ----
  conv_gemm_k<3072, 1, 2, 2, 2048, true, false, 16><<<dim3(2, 16, 16), 256, 0, stream>>>(Shi, Slo, Wf1, nullptr, C, nullptr);
  reduce_bn_k<256, 2048, 16, 4><<<dim3(32, 4), 256, 0, stream>>>(C, G6, PART);
  bn_finalize<<<2048, 64, 0, stream>>>(PART, g6, b6, SC, SH, 4, 1.f / 256.f);
  bn1d_apply_cc_k<<<256, 256, 0, stream>>>(G6, SC, SH, CChi, CClo);

  // ---- FC2 (2-pass, split-K=16): [256][8192] x [2048][8192] ----
  conv_gemm_k<8192, 1, 2, 2, 2048, true, false, 16><<<dim3(2, 16, 16), 256, 0, stream>>>(CChi, CClo, Wf2, nullptr, C, nullptr);
  reduce_bn_k<256, 2048, 16, 4><<<dim3(32, 4), 256, 0, stream>>>(C, G7, PART);
  bn_finalize<<<2048, 64, 0, stream>>>(PART, g7, b7, SC, SH, 4, 1.f / 256.f);
  bn1d_apply_f32_k<<<512, 256, 0, stream>>>(G7, SC, SH, out);
}